// Round 2
// baseline (508.348 us; speedup 1.0000x reference)
//
#include <hip/hip_runtime.h>
#include <stdint.h>

typedef __attribute__((ext_vector_type(4))) float f32x4;
typedef __attribute__((ext_vector_type(8))) short s16x8;
typedef __attribute__((ext_vector_type(4))) short s16x4;
typedef __attribute__((ext_vector_type(8))) unsigned short u16x8;

#define NB 8
#define HH 56
#define WW0 56
#define NC 384
#define NQTOK (HH*WW0)     // 3136
#define HKV 28
#define NKTOK (HKV*HKV)    // 784
#define NHEAD 6
#define HDIM 64

__device__ __forceinline__ float bf2f(unsigned short u) {
    union { unsigned int i; float f; } x; x.i = ((unsigned int)u) << 16; return x.f;
}
__device__ __forceinline__ unsigned short f2bf(float f) {
    union { float f; unsigned int i; } x; x.f = f;
    unsigned int r = x.i + 0x7FFFu + ((x.i >> 16) & 1u);
    return (unsigned short)(r >> 16);
}

// C[m, o] = sum_k A[m,k] * W[o,k] + bias[o]
// A: Mx384 (f32 or bf16), W: 384x384 f32 row-major (O x K), out bf16 or f32.
// Tile 128x128, BK=64, 4 waves (2x2), each wave 64x64 via 4x4 mfma_16x16x32 fragments.
template<bool A_IS_F32, bool OUT_IS_F32>
__global__ __launch_bounds__(256) void gemm_bt(
    const void* __restrict__ Ap,
    const float* __restrict__ Wa, const float* __restrict__ Wb, const float* __restrict__ Wc,
    const float* __restrict__ Ba, const float* __restrict__ Bb, const float* __restrict__ Bc,
    void* __restrict__ Oa, void* __restrict__ Ob, void* __restrict__ Oc,
    int mtiles)
{
    __shared__ unsigned short lA[128*64];
    __shared__ unsigned short lW[128*64];
    const int bid = blockIdx.x;
    const int mt = bid % mtiles;
    const int nt = bid / mtiles;
    const int mat = nt / 3;
    const int ncol = nt - mat*3;
    const float* Wsel = (mat==0) ? Wa : ((mat==1) ? Wb : Wc);
    const float* Bsel = (mat==0) ? Ba : ((mat==1) ? Bb : Bc);
    void* Osel        = (mat==0) ? Oa : ((mat==1) ? Ob : Oc);
    const int Mbase = mt*128, Nbase = ncol*128;
    const int t = threadIdx.x;
    const int w = t >> 6, l = t & 63;
    const int wr = w >> 1, wc = w & 1;
    const int lr = l & 15, lg = l >> 4;

    f32x4 acc[4][4] = {};
    for (int kt = 0; kt < 6; ++kt) {
        __syncthreads();
        #pragma unroll
        for (int i = 0; i < 4; ++i) {
            int c = i*256 + t;
            int row = c >> 3, c8 = c & 7;
            size_t asrc = (size_t)(Mbase+row)*NC + kt*64 + c8*8;
            if (A_IS_F32) {
                const float* Af = (const float*)Ap;
                f32x4 a0 = *(const f32x4*)&Af[asrc];
                f32x4 a1 = *(const f32x4*)&Af[asrc + 4];
                u16x8 pk;
                #pragma unroll
                for (int j = 0; j < 4; ++j) { pk[j] = f2bf(a0[j]); pk[j+4] = f2bf(a1[j]); }
                *(u16x8*)&lA[c*8] = pk;
            } else {
                *(u16x8*)&lA[c*8] = *(const u16x8*)&((const unsigned short*)Ap)[asrc];
            }
            size_t wsrc = (size_t)(Nbase+row)*NC + kt*64 + c8*8;
            f32x4 w0 = *(const f32x4*)&Wsel[wsrc];
            f32x4 w1 = *(const f32x4*)&Wsel[wsrc + 4];
            u16x8 wk;
            #pragma unroll
            for (int j = 0; j < 4; ++j) { wk[j] = f2bf(w0[j]); wk[j+4] = f2bf(w1[j]); }
            *(u16x8*)&lW[c*8] = wk;
        }
        __syncthreads();
        #pragma unroll
        for (int kk = 0; kk < 2; ++kk) {
            s16x8 af[4], bfr[4];
            #pragma unroll
            for (int m = 0; m < 4; ++m)
                af[m] = *(const s16x8*)&lA[(wr*64 + m*16 + lr)*64 + kk*32 + lg*8];
            #pragma unroll
            for (int n = 0; n < 4; ++n)
                bfr[n] = *(const s16x8*)&lW[(wc*64 + n*16 + lr)*64 + kk*32 + lg*8];
            #pragma unroll
            for (int m = 0; m < 4; ++m)
                #pragma unroll
                for (int n = 0; n < 4; ++n)
                    acc[m][n] = __builtin_amdgcn_mfma_f32_16x16x32_bf16(af[m], bfr[n], acc[m][n], 0, 0, 0);
        }
    }
    // Epilogue: D layout col = l&15, row = (l>>4)*4 + reg
    #pragma unroll
    for (int n = 0; n < 4; ++n) {
        int col = Nbase + wc*64 + n*16 + lr;
        float bias = Bsel[col];
        #pragma unroll
        for (int m = 0; m < 4; ++m) {
            int row0 = Mbase + wr*64 + m*16 + lg*4;
            #pragma unroll
            for (int r = 0; r < 4; ++r) {
                float vv = acc[m][n][r] + bias;
                if (OUT_IS_F32) ((float*)Osel)[(size_t)(row0 + r)*NC + col] = vv;
                else ((unsigned short*)Osel)[(size_t)(row0 + r)*NC + col] = f2bf(vv);
            }
        }
    }
}

// Depthwise 3x3 conv, pad 1, stride S, token layout (NB, 56*56, NC) -> (NB, HO*WO, NC)
// input bf16, weights/bias f32, output bf16
template<int S, int HO, int WO>
__global__ __launch_bounds__(256) void dwconv(
    const unsigned short* __restrict__ in,
    const float* __restrict__ wdw,   // (NC, 9)
    const float* __restrict__ bias,  // (NC)
    unsigned short* __restrict__ outp)
{
    const int nc8 = NC/8;
    int idx = blockIdx.x*256 + threadIdx.x;
    if (idx >= NB*HO*WO*nc8) return;
    int c8 = idx % nc8; int rest = idx / nc8;
    int wo = rest % WO; rest /= WO;
    int ho = rest % HO; int b = rest / HO;
    int c0 = c8*8;
    float acc[8];
    #pragma unroll
    for (int j = 0; j < 8; ++j) acc[j] = bias[c0+j];
    #pragma unroll
    for (int kh = 0; kh < 3; ++kh) {
        int h = ho*S + kh - 1;
        if (h < 0 || h >= HH) continue;
        #pragma unroll
        for (int kw = 0; kw < 3; ++kw) {
            int ww = wo*S + kw - 1;
            if (ww < 0 || ww >= WW0) continue;
            u16x8 xv = *(const u16x8*)&in[((size_t)b*(HH*WW0) + h*WW0 + ww)*NC + c0];
            #pragma unroll
            for (int j = 0; j < 8; ++j)
                acc[j] += bf2f(xv[j]) * wdw[(c0+j)*9 + kh*3 + kw];
        }
    }
    u16x8 ov;
    #pragma unroll
    for (int j = 0; j < 8; ++j) ov[j] = f2bf(acc[j]);
    *(u16x8*)&outp[((size_t)b*(HO*WO) + ho*WO + wo)*NC + c0] = ov;
}

// Flash-style attention with sign(s)*softmax(|s|).
// Per wave: 16 q rows. S^T = mfma16x16x32(K_frag, Q_frag): lane l holds S[k=kb+(l>>4)*4+r][q=q0+(l&15)].
// D-layout == B-operand layout of mfma_16x16x16bf16_1k, so signed P feeds PV directly (zero shuffles).
__global__ __launch_bounds__(256) void attn_fwd(
    const unsigned short* __restrict__ Q,   // (NB, 3136, 384) bf16
    const unsigned short* __restrict__ K,   // (NB, 784, 384) bf16
    const unsigned short* __restrict__ V,   // (NB, 784, 384) bf16
    unsigned short* __restrict__ ctx)       // (NB, 3136, 384) bf16
{
    const float scale = 0.125f;  // 64^-0.5
    const int bid = blockIdx.x;
    const int qt = bid % (NQTOK/64);
    const int bh = bid / (NQTOK/64);
    const int b = bh / NHEAD, h = bh - b*NHEAD;
    const int t = threadIdx.x;
    const int w = t >> 6, l = t & 63;
    const int lq = l & 15, lg = l >> 4;
    const int q0 = qt*64 + w*16;
    const size_t qoff = ((size_t)b*NQTOK + q0 + lq)*NC + h*HDIM;
    s16x8 qf0 = *(const s16x8*)&Q[qoff + lg*8];
    s16x8 qf1 = *(const s16x8*)&Q[qoff + 32 + lg*8];

    float mrun = 0.f, lrun = 0.f;
    f32x4 oacc[4] = {};
    for (int kt = 0; kt < NKTOK/16; ++kt) {
        int kbase = kt*16;
        const size_t koff = ((size_t)b*NKTOK + kbase + lq)*NC + h*HDIM;
        s16x8 kf0 = *(const s16x8*)&K[koff + lg*8];
        s16x8 kf1 = *(const s16x8*)&K[koff + 32 + lg*8];
        f32x4 st = {};
        st = __builtin_amdgcn_mfma_f32_16x16x32_bf16(kf0, qf0, st, 0, 0, 0);
        st = __builtin_amdgcn_mfma_f32_16x16x32_bf16(kf1, qf1, st, 0, 0, 0);
        float sv[4], av[4], tm = 0.f;
        #pragma unroll
        for (int r = 0; r < 4; ++r) { sv[r] = st[r]*scale; av[r] = fabsf(sv[r]); tm = fmaxf(tm, av[r]); }
        tm = fmaxf(tm, __shfl_xor(tm, 16));
        tm = fmaxf(tm, __shfl_xor(tm, 32));
        float mnew = fmaxf(mrun, tm);
        float corr = __expf(mrun - mnew);
        float ev[4], rs = 0.f;
        #pragma unroll
        for (int r = 0; r < 4; ++r) { ev[r] = __expf(av[r] - mnew); rs += ev[r]; }
        rs += __shfl_xor(rs, 16);
        rs += __shfl_xor(rs, 32);
        lrun = lrun*corr + rs;
        mrun = mnew;
        s16x4 pbv;
        #pragma unroll
        for (int r = 0; r < 4; ++r) {
            float p = (sv[r] > 0.f) ? ev[r] : ((sv[r] < 0.f) ? -ev[r] : 0.f);
            pbv[r] = (short)f2bf(p);
        }
        #pragma unroll
        for (int f = 0; f < 4; ++f) {
            #pragma unroll
            for (int r = 0; r < 4; ++r) oacc[f][r] *= corr;
            s16x4 vbv;  // A operand: V^T[dv = f*16+lq][k = kbase+lg*4+j]
            #pragma unroll
            for (int j = 0; j < 4; ++j)
                vbv[j] = (short)V[((size_t)b*NKTOK + kbase + lg*4 + j)*NC + h*HDIM + f*16 + lq];
            oacc[f] = __builtin_amdgcn_mfma_f32_16x16x16bf16_1k(vbv, pbv, oacc[f], 0, 0, 0);
        }
    }
    float inv = 1.f / lrun;
    #pragma unroll
    for (int f = 0; f < 4; ++f)
        #pragma unroll
        for (int r = 0; r < 4; ++r)
            ctx[((size_t)b*NQTOK + q0 + lq)*NC + h*HDIM + f*16 + lg*4 + r] = f2bf(oacc[f][r]*inv);
}

extern "C" void kernel_launch(void* const* d_in, const int* in_sizes, int n_in,
                              void* d_out, int out_size, void* d_ws, size_t ws_size,
                              hipStream_t stream)
{
    (void)in_sizes; (void)n_in; (void)out_size; (void)ws_size;
    const float* x      = (const float*)d_in[0];
    // d_in[1] = H, d_in[2] = W (int scalars, fixed 56)
    const float* q_w    = (const float*)d_in[3];
    const float* q_b    = (const float*)d_in[4];
    const float* k_w    = (const float*)d_in[5];
    const float* k_b    = (const float*)d_in[6];
    const float* v_w    = (const float*)d_in[7];
    const float* v_b    = (const float*)d_in[8];
    const float* q_dw_w = (const float*)d_in[9];
    const float* q_dw_b = (const float*)d_in[10];
    const float* k_dw_w = (const float*)d_in[11];
    const float* k_dw_b = (const float*)d_in[12];
    const float* v_dw_w = (const float*)d_in[13];
    const float* v_dw_b = (const float*)d_in[14];
    const float* proj_w = (const float*)d_in[15];
    const float* proj_b = (const float*)d_in[16];
    float* outf = (float*)d_out;
    unsigned short* ws  = (unsigned short*)d_ws;

    const size_t nQ  = (size_t)NB*NQTOK*NC;   // 9,633,792 elems
    const size_t nKc = (size_t)NB*NKTOK*NC;   // 2,408,448 elems
    unsigned short* preQ = ws;                // bf16 pre-conv Q
    unsigned short* preK = ws + nQ;           // bf16 pre-conv K; later ctx
    unsigned short* Kc   = ws + 2*nQ;         // bf16 post-conv K
    unsigned short* Vc   = Kc + nKc;          // bf16 post-conv V
    unsigned short* preV = (unsigned short*)d_out;  // bf16 pre-conv V (d_out scratch)
    unsigned short* Qc   = (unsigned short*)d_out;  // bf16 post-conv Q (after preV consumed)
    unsigned short* ctx  = preK;              // reuse preK space after conv_k
    // total ws = 48.2 MB

    // 1. QKV projections: x(f32) @ W^T -> bf16 Q,K,V
    gemm_bt<true,false><<<dim3(196*9), dim3(256), 0, stream>>>(
        x, q_w, k_w, v_w, q_b, k_b, v_b, preQ, preK, preV, 196);
    // 2. depthwise convs (k,v stride 2 first so their sources free up)
    dwconv<2,28,28><<<dim3(1176), dim3(256), 0, stream>>>(preK, k_dw_w, k_dw_b, Kc);
    dwconv<2,28,28><<<dim3(1176), dim3(256), 0, stream>>>(preV, v_dw_w, v_dw_b, Vc);
    dwconv<1,56,56><<<dim3(4704), dim3(256), 0, stream>>>(preQ, q_dw_w, q_dw_b, Qc);
    // 3. attention: reads Qc(d_out), Kc, Vc; writes ctx (preK space)
    attn_fwd<<<dim3(2352), dim3(256), 0, stream>>>(Qc, Kc, Vc, ctx);
    // 4. output projection: ctx(bf16) @ proj_w^T + proj_b -> f32 d_out
    gemm_bt<false,true><<<dim3(196*3), dim3(256), 0, stream>>>(
        ctx, proj_w, proj_w, proj_w, proj_b, proj_b, proj_b, outf, outf, outf, 196);
}

// Round 3
// 454.351 us; speedup vs baseline: 1.1188x; 1.1188x over previous
//
#include <hip/hip_runtime.h>
#include <hip/hip_bf16.h>
#include <stdint.h>

typedef __attribute__((ext_vector_type(4))) float f32x4;
typedef __attribute__((ext_vector_type(8))) short s16x8;
typedef __attribute__((ext_vector_type(4))) short s16x4;
typedef __attribute__((ext_vector_type(8))) unsigned short u16x8;

#define NB 8
#define HH 56
#define WW0 56
#define NC 384
#define NQTOK (HH*WW0)     // 3136
#define HKV 28
#define NKTOK (HKV*HKV)    // 784
#define NHEAD 6
#define HDIM 64
#define LOG2E 1.44269504f

__device__ __forceinline__ float bf2f(unsigned short u) {
    union { unsigned int i; float f; } x; x.i = ((unsigned int)u) << 16; return x.f;
}
__device__ __forceinline__ unsigned short f2bf(float f) {
    union { float f; unsigned int i; } x; x.f = f;
    unsigned int r = x.i + 0x7FFFu + ((x.i >> 16) & 1u);
    return (unsigned short)(r >> 16);
}
__device__ __forceinline__ short f2bf_hw(float f) {
    __hip_bfloat16 hb = __float2bfloat16(f);
    return *reinterpret_cast<short*>(&hb);
}

// C[m, o] = sum_k A[m,k] * W[o,k] + bias[o]
// A: Mx384 (f32 or bf16), W: 384x384 f32 row-major (O x K), out bf16 or f32.
// Tile 128x128, BK=64, 4 waves (2x2). nt-major block order: blocks sharing an
// A-tile are temporally adjacent -> A fetched from HBM ~once (L2/L3 serves reuse).
template<bool A_IS_F32, bool OUT_IS_F32>
__global__ __launch_bounds__(256) void gemm_bt(
    const void* __restrict__ Ap,
    const float* __restrict__ Wa, const float* __restrict__ Wb, const float* __restrict__ Wc,
    const float* __restrict__ Ba, const float* __restrict__ Bb, const float* __restrict__ Bc,
    void* __restrict__ Oa, void* __restrict__ Ob, void* __restrict__ Oc,
    int ntiles)
{
    __shared__ unsigned short lA[128*64];
    __shared__ unsigned short lW[128*64];
    const int bid = blockIdx.x;
    const int nt = bid % ntiles;      // nt-major: A-tile reuse is temporally local
    const int mt = bid / ntiles;
    const int mat = nt / 3;
    const int ncol = nt - mat*3;
    const float* Wsel = (mat==0) ? Wa : ((mat==1) ? Wb : Wc);
    const float* Bsel = (mat==0) ? Ba : ((mat==1) ? Bb : Bc);
    void* Osel        = (mat==0) ? Oa : ((mat==1) ? Ob : Oc);
    const int Mbase = mt*128, Nbase = ncol*128;
    const int t = threadIdx.x;
    const int w = t >> 6, l = t & 63;
    const int wr = w >> 1, wc = w & 1;
    const int lr = l & 15, lg = l >> 4;

    f32x4 acc[4][4] = {};
    for (int kt = 0; kt < 6; ++kt) {
        __syncthreads();
        #pragma unroll
        for (int i = 0; i < 4; ++i) {
            int c = i*256 + t;
            int row = c >> 3, c8 = c & 7;
            size_t asrc = (size_t)(Mbase+row)*NC + kt*64 + c8*8;
            if (A_IS_F32) {
                const float* Af = (const float*)Ap;
                f32x4 a0 = *(const f32x4*)&Af[asrc];
                f32x4 a1 = *(const f32x4*)&Af[asrc + 4];
                u16x8 pk;
                #pragma unroll
                for (int j = 0; j < 4; ++j) { pk[j] = f2bf(a0[j]); pk[j+4] = f2bf(a1[j]); }
                *(u16x8*)&lA[c*8] = pk;
            } else {
                *(u16x8*)&lA[c*8] = *(const u16x8*)&((const unsigned short*)Ap)[asrc];
            }
            size_t wsrc = (size_t)(Nbase+row)*NC + kt*64 + c8*8;
            f32x4 w0 = *(const f32x4*)&Wsel[wsrc];
            f32x4 w1 = *(const f32x4*)&Wsel[wsrc + 4];
            u16x8 wk;
            #pragma unroll
            for (int j = 0; j < 4; ++j) { wk[j] = f2bf(w0[j]); wk[j+4] = f2bf(w1[j]); }
            *(u16x8*)&lW[c*8] = wk;
        }
        __syncthreads();
        #pragma unroll
        for (int kk = 0; kk < 2; ++kk) {
            s16x8 af[4], bfr[4];
            #pragma unroll
            for (int m = 0; m < 4; ++m)
                af[m] = *(const s16x8*)&lA[(wr*64 + m*16 + lr)*64 + kk*32 + lg*8];
            #pragma unroll
            for (int n = 0; n < 4; ++n)
                bfr[n] = *(const s16x8*)&lW[(wc*64 + n*16 + lr)*64 + kk*32 + lg*8];
            #pragma unroll
            for (int m = 0; m < 4; ++m)
                #pragma unroll
                for (int n = 0; n < 4; ++n)
                    acc[m][n] = __builtin_amdgcn_mfma_f32_16x16x32_bf16(af[m], bfr[n], acc[m][n], 0, 0, 0);
        }
    }
    #pragma unroll
    for (int n = 0; n < 4; ++n) {
        int col = Nbase + wc*64 + n*16 + lr;
        float bias = Bsel[col];
        #pragma unroll
        for (int m = 0; m < 4; ++m) {
            int row0 = Mbase + wr*64 + m*16 + lg*4;
            #pragma unroll
            for (int r = 0; r < 4; ++r) {
                float vv = acc[m][n][r] + bias;
                if (OUT_IS_F32) ((float*)Osel)[(size_t)(row0 + r)*NC + col] = vv;
                else ((unsigned short*)Osel)[(size_t)(row0 + r)*NC + col] = f2bf(vv);
            }
        }
    }
}

// Depthwise 3x3 conv, pad 1, stride S, token layout (NB, 56*56, NC) -> (NB, HO*WO, NC)
// input bf16, weights/bias f32, output bf16.
// SCALE: multiply output by 0.125 (folds attention's 1/sqrt(64) into Q).
// TRANS: write transposed layout Vt[(b*6+h)*64 + d][tok] for attention's V^T operand.
template<int S, int HO, int WO, bool SCALE, bool TRANS>
__global__ __launch_bounds__(256) void dwconv(
    const unsigned short* __restrict__ in,
    const float* __restrict__ wdw,   // (NC, 9)
    const float* __restrict__ bias,  // (NC)
    unsigned short* __restrict__ outp)
{
    const int nc8 = NC/8;
    int idx = blockIdx.x*256 + threadIdx.x;
    if (idx >= NB*HO*WO*nc8) return;
    int c8 = idx % nc8; int rest = idx / nc8;
    int wo = rest % WO; rest /= WO;
    int ho = rest % HO; int b = rest / HO;
    int c0 = c8*8;
    float acc[8];
    #pragma unroll
    for (int j = 0; j < 8; ++j) acc[j] = bias[c0+j];
    #pragma unroll
    for (int kh = 0; kh < 3; ++kh) {
        int h = ho*S + kh - 1;
        if (h < 0 || h >= HH) continue;
        #pragma unroll
        for (int kw = 0; kw < 3; ++kw) {
            int ww = wo*S + kw - 1;
            if (ww < 0 || ww >= WW0) continue;
            u16x8 xv = *(const u16x8*)&in[((size_t)b*(HH*WW0) + h*WW0 + ww)*NC + c0];
            #pragma unroll
            for (int j = 0; j < 8; ++j)
                acc[j] += bf2f(xv[j]) * wdw[(c0+j)*9 + kh*3 + kw];
        }
    }
    if (SCALE) {
        #pragma unroll
        for (int j = 0; j < 8; ++j) acc[j] *= 0.125f;
    }
    int tok = ho*WO + wo;
    if (TRANS) {
        int hh = c0 >> 6, d0 = c0 & 63;
        size_t base = ((size_t)(b*NHEAD + hh)*HDIM + d0)*(HO*WO) + tok;
        #pragma unroll
        for (int j = 0; j < 8; ++j)
            outp[base + (size_t)j*(HO*WO)] = f2bf(acc[j]);
    } else {
        u16x8 ov;
        #pragma unroll
        for (int j = 0; j < 8; ++j) ov[j] = f2bf(acc[j]);
        *(u16x8*)&outp[((size_t)b*(HO*WO) + tok)*NC + c0] = ov;
    }
}

// Flash-style attention, sign(s)*softmax(|s|), Q pre-scaled by 1/8.
// Per wave: 32 q rows (2 x 16-row fragments), KVBLK=64, no LDS, no barriers.
// S^T = mfma16x16x32(K_frag, Q_frag): lane holds S[k=kbase+kfr*16+lg*4+r][q=q0+lq].
// S^T D-layout == B-operand layout of mfma_16x16x16bf16_1k -> P feeds PV with zero shuffles.
// V^T A-fragments come as single 8B loads from the pre-transposed Vt[b,h,d,k].
__global__ __launch_bounds__(256) void attn_fwd(
    const unsigned short* __restrict__ Q,   // (NB, 3136, 384) bf16, pre-scaled
    const unsigned short* __restrict__ K,   // (NB, 784, 384) bf16
    const unsigned short* __restrict__ Vt,  // (NB*6, 64, 784) bf16 transposed
    unsigned short* __restrict__ ctx)       // (NB, 3136, 384) bf16
{
    const int bid = blockIdx.x;
    const int qt = bid % 25;
    const int bh = bid / 25;
    const int b = bh / NHEAD, h = bh - b*NHEAD;
    const int t = threadIdx.x;
    const int w = t >> 6, l = t & 63;
    const int lq = l & 15, lg = l >> 4;
    const int wq0 = qt*128 + w*32;
    if (wq0 >= NQTOK) return;

    const unsigned short* Qb = Q + ((size_t)b*NQTOK + wq0 + lq)*NC + h*HDIM;
    s16x8 qA[2][2];
    qA[0][0] = *(const s16x8*)&Qb[lg*8];
    qA[0][1] = *(const s16x8*)&Qb[32 + lg*8];
    qA[1][0] = *(const s16x8*)&Qb[16*NC + lg*8];
    qA[1][1] = *(const s16x8*)&Qb[16*NC + 32 + lg*8];

    const unsigned short* Kb = K + (size_t)b*NKTOK*NC + h*HDIM;
    const unsigned short* Vb = Vt + (size_t)bh*HDIM*NKTOK;

    float mrun[2] = {0.f, 0.f}, lrun[2] = {0.f, 0.f};
    f32x4 oacc[2][4] = {};

    for (int kt = 0; kt < 12; ++kt) {
        const int kbase = kt*64;
        f32x4 st[2][4] = {};
        #pragma unroll
        for (int kfr = 0; kfr < 4; ++kfr) {
            const unsigned short* kr = &Kb[(size_t)(kbase + kfr*16 + lq)*NC];
            s16x8 kf0 = *(const s16x8*)&kr[lg*8];
            s16x8 kf1 = *(const s16x8*)&kr[32 + lg*8];
            st[0][kfr] = __builtin_amdgcn_mfma_f32_16x16x32_bf16(kf0, qA[0][0], st[0][kfr], 0,0,0);
            st[0][kfr] = __builtin_amdgcn_mfma_f32_16x16x32_bf16(kf1, qA[0][1], st[0][kfr], 0,0,0);
            st[1][kfr] = __builtin_amdgcn_mfma_f32_16x16x32_bf16(kf0, qA[1][0], st[1][kfr], 0,0,0);
            st[1][kfr] = __builtin_amdgcn_mfma_f32_16x16x32_bf16(kf1, qA[1][1], st[1][kfr], 0,0,0);
        }
        // V^T fragments (shared by both q-fragments); independent of S -> issued early
        s16x4 vv[4][4];
        #pragma unroll
        for (int ks = 0; ks < 4; ++ks)
            #pragma unroll
            for (int f = 0; f < 4; ++f)
                vv[ks][f] = *(const s16x4*)&Vb[(size_t)(f*16 + lq)*NKTOK + kbase + ks*16 + lg*4];
        // online signed softmax in log2 domain
        s16x4 pbv[2][4];
        #pragma unroll
        for (int qf = 0; qf < 2; ++qf) {
            float av[4][4], tm = 0.f;
            #pragma unroll
            for (int kfr = 0; kfr < 4; ++kfr)
                #pragma unroll
                for (int r = 0; r < 4; ++r) {
                    av[kfr][r] = LOG2E * fabsf(st[qf][kfr][r]);
                    tm = fmaxf(tm, av[kfr][r]);
                }
            tm = fmaxf(tm, __shfl_xor(tm, 16));
            tm = fmaxf(tm, __shfl_xor(tm, 32));
            if (!__all(tm <= mrun[qf] + 11.5416f)) {   // defer-max, THR = 8*log2e
                float mnew = fmaxf(mrun[qf], tm);
                float corr = exp2f(mrun[qf] - mnew);
                #pragma unroll
                for (int f = 0; f < 4; ++f)
                    #pragma unroll
                    for (int r = 0; r < 4; ++r) oacc[qf][f][r] *= corr;
                lrun[qf] *= corr;
                mrun[qf] = mnew;
            }
            float rs = 0.f;
            #pragma unroll
            for (int kfr = 0; kfr < 4; ++kfr)
                #pragma unroll
                for (int r = 0; r < 4; ++r) {
                    float e = exp2f(av[kfr][r] - mrun[qf]);
                    rs += e;
                    pbv[qf][kfr][r] = f2bf_hw(copysignf(e, st[qf][kfr][r]));
                }
            rs += __shfl_xor(rs, 16);
            rs += __shfl_xor(rs, 32);
            lrun[qf] += rs;
        }
        // PV
        #pragma unroll
        for (int ks = 0; ks < 4; ++ks)
            #pragma unroll
            for (int f = 0; f < 4; ++f) {
                oacc[0][f] = __builtin_amdgcn_mfma_f32_16x16x16bf16_1k(vv[ks][f], pbv[0][ks], oacc[0][f], 0,0,0);
                oacc[1][f] = __builtin_amdgcn_mfma_f32_16x16x16bf16_1k(vv[ks][f], pbv[1][ks], oacc[1][f], 0,0,0);
            }
    }
    // tail: k = 768..783 (16 rows, exactly one fragment)
    {
        const int kbase = 768;
        const unsigned short* kr = &Kb[(size_t)(kbase + lq)*NC];
        s16x8 kf0 = *(const s16x8*)&kr[lg*8];
        s16x8 kf1 = *(const s16x8*)&kr[32 + lg*8];
        f32x4 st[2] = {};
        st[0] = __builtin_amdgcn_mfma_f32_16x16x32_bf16(kf0, qA[0][0], st[0], 0,0,0);
        st[0] = __builtin_amdgcn_mfma_f32_16x16x32_bf16(kf1, qA[0][1], st[0], 0,0,0);
        st[1] = __builtin_amdgcn_mfma_f32_16x16x32_bf16(kf0, qA[1][0], st[1], 0,0,0);
        st[1] = __builtin_amdgcn_mfma_f32_16x16x32_bf16(kf1, qA[1][1], st[1], 0,0,0);
        s16x4 vv[4];
        #pragma unroll
        for (int f = 0; f < 4; ++f)
            vv[f] = *(const s16x4*)&Vb[(size_t)(f*16 + lq)*NKTOK + kbase + lg*4];
        s16x4 pbv[2];
        #pragma unroll
        for (int qf = 0; qf < 2; ++qf) {
            float av[4], tm = 0.f;
            #pragma unroll
            for (int r = 0; r < 4; ++r) { av[r] = LOG2E * fabsf(st[qf][r]); tm = fmaxf(tm, av[r]); }
            tm = fmaxf(tm, __shfl_xor(tm, 16));
            tm = fmaxf(tm, __shfl_xor(tm, 32));
            if (!__all(tm <= mrun[qf] + 11.5416f)) {
                float mnew = fmaxf(mrun[qf], tm);
                float corr = exp2f(mrun[qf] - mnew);
                #pragma unroll
                for (int f = 0; f < 4; ++f)
                    #pragma unroll
                    for (int r = 0; r < 4; ++r) oacc[qf][f][r] *= corr;
                lrun[qf] *= corr;
                mrun[qf] = mnew;
            }
            float rs = 0.f;
            #pragma unroll
            for (int r = 0; r < 4; ++r) {
                float e = exp2f(av[r] - mrun[qf]);
                rs += e;
                pbv[qf][r] = f2bf_hw(copysignf(e, st[qf][r]));
            }
            rs += __shfl_xor(rs, 16);
            rs += __shfl_xor(rs, 32);
            lrun[qf] += rs;
        }
        #pragma unroll
        for (int f = 0; f < 4; ++f) {
            oacc[0][f] = __builtin_amdgcn_mfma_f32_16x16x16bf16_1k(vv[f], pbv[0], oacc[0][f], 0,0,0);
            oacc[1][f] = __builtin_amdgcn_mfma_f32_16x16x16bf16_1k(vv[f], pbv[1], oacc[1][f], 0,0,0);
        }
    }
    // store
    #pragma unroll
    for (int qf = 0; qf < 2; ++qf) {
        float inv = 1.f / lrun[qf];
        unsigned short* cb = ctx + ((size_t)b*NQTOK + wq0 + qf*16 + lq)*NC + h*HDIM;
        #pragma unroll
        for (int f = 0; f < 4; ++f) {
            s16x4 o;
            #pragma unroll
            for (int r = 0; r < 4; ++r) o[r] = (short)f2bf(oacc[qf][f][r] * inv);
            *(s16x4*)&cb[f*16 + lg*4] = o;
        }
    }
}

extern "C" void kernel_launch(void* const* d_in, const int* in_sizes, int n_in,
                              void* d_out, int out_size, void* d_ws, size_t ws_size,
                              hipStream_t stream)
{
    (void)in_sizes; (void)n_in; (void)out_size; (void)ws_size;
    const float* x      = (const float*)d_in[0];
    const float* q_w    = (const float*)d_in[3];
    const float* q_b    = (const float*)d_in[4];
    const float* k_w    = (const float*)d_in[5];
    const float* k_b    = (const float*)d_in[6];
    const float* v_w    = (const float*)d_in[7];
    const float* v_b    = (const float*)d_in[8];
    const float* q_dw_w = (const float*)d_in[9];
    const float* q_dw_b = (const float*)d_in[10];
    const float* k_dw_w = (const float*)d_in[11];
    const float* k_dw_b = (const float*)d_in[12];
    const float* v_dw_w = (const float*)d_in[13];
    const float* v_dw_b = (const float*)d_in[14];
    const float* proj_w = (const float*)d_in[15];
    const float* proj_b = (const float*)d_in[16];
    float* outf = (float*)d_out;
    unsigned short* ws  = (unsigned short*)d_ws;

    const size_t nQ  = (size_t)NB*NQTOK*NC;   // 9,633,792 elems
    const size_t nKc = (size_t)NB*NKTOK*NC;   // 2,408,448 elems
    unsigned short* preQ = ws;                // bf16 pre-conv Q
    unsigned short* preK = ws + nQ;           // bf16 pre-conv K; later ctx
    unsigned short* Kc   = ws + 2*nQ;         // bf16 post-conv K
    unsigned short* Vt   = Kc + nKc;          // bf16 post-conv V, TRANSPOSED (b,h,d,k)
    unsigned short* preV = (unsigned short*)d_out;  // bf16 pre-conv V (d_out scratch)
    unsigned short* Qc   = (unsigned short*)d_out;  // bf16 post-conv Q (after preV consumed)
    unsigned short* ctx  = preK;              // reuse preK space after conv_k

    // 1. QKV projections: x(f32) @ W^T -> bf16 Q,K,V
    gemm_bt<true,false><<<dim3(196*9), dim3(256), 0, stream>>>(
        x, q_w, k_w, v_w, q_b, k_b, v_b, preQ, preK, preV, 9);
    // 2. depthwise convs; K normal, V transposed, Q scaled by 1/8
    dwconv<2,28,28,false,false><<<dim3(1176), dim3(256), 0, stream>>>(preK, k_dw_w, k_dw_b, Kc);
    dwconv<2,28,28,false,true ><<<dim3(1176), dim3(256), 0, stream>>>(preV, v_dw_w, v_dw_b, Vt);
    dwconv<1,56,56,true ,false><<<dim3(4704), dim3(256), 0, stream>>>(preQ, q_dw_w, q_dw_b, Qc);
    // 3. attention: 48 bh x 25 q-tiles of 128
    attn_fwd<<<dim3(1200), dim3(256), 0, stream>>>(Qc, Kc, Vt, ctx);
    // 4. output projection: ctx(bf16) @ proj_w^T + proj_b -> f32 d_out
    gemm_bt<false,true><<<dim3(196*3), dim3(256), 0, stream>>>(
        ctx, proj_w, proj_w, proj_w, proj_b, proj_b, proj_b, outf, outf, outf, 3);
}

// Round 4
// 256.896 us; speedup vs baseline: 1.9788x; 1.7686x over previous
//
#include <hip/hip_runtime.h>
#include <hip/hip_bf16.h>
#include <stdint.h>

typedef __attribute__((ext_vector_type(4))) float f32x4;
typedef __attribute__((ext_vector_type(8))) short s16x8;
typedef __attribute__((ext_vector_type(4))) short s16x4;
typedef __attribute__((ext_vector_type(8))) unsigned short u16x8;

#define NB 8
#define HH 56
#define WW0 56
#define NC 384
#define NQTOK (HH*WW0)     // 3136
#define HKV 28
#define NKTOK (HKV*HKV)    // 784
#define NHEAD 6
#define HDIM 64
#define LOG2E 1.44269504f

__device__ __forceinline__ float bf2f(unsigned short u) {
    union { unsigned int i; float f; } x; x.i = ((unsigned int)u) << 16; return x.f;
}
__device__ __forceinline__ unsigned short f2bf(float f) {
    union { float f; unsigned int i; } x; x.f = f;
    unsigned int r = x.i + 0x7FFFu + ((x.i >> 16) & 1u);
    return (unsigned short)(r >> 16);
}
__device__ __forceinline__ short f2bf_hw(float f) {
    __hip_bfloat16 hb = __float2bfloat16(f);
    return *reinterpret_cast<short*>(&hb);
}

// Transpose dw weights (NC,9) -> (9,NC) for coalesced vector loads in dwconv.
__global__ __launch_bounds__(256) void prep_w(
    const float* __restrict__ qw, const float* __restrict__ kw, const float* __restrict__ vw,
    float* __restrict__ wt)   // [3][9][NC]
{
    int i = blockIdx.x*256 + threadIdx.x;
    if (i >= 3*9*NC) return;
    int m = i / (9*NC); int r = i - m*(9*NC);
    int tap = r / NC; int c = r - tap*NC;
    const float* src = (m==0) ? qw : ((m==1) ? kw : vw);
    wt[i] = src[c*9 + tap];
}

// C[m, o] = sum_k A[m,k] * W[o,k] + bias[o]
// A: Mx384 (f32 or bf16), W: 384x384 f32 row-major (O x K), out bf16 or f32.
// Tile 128x128, BK=64, 4 waves (2x2). nt-major block order: blocks sharing an
// A-tile are temporally adjacent -> A fetched from HBM ~once (L2/L3 serves reuse).
template<bool A_IS_F32, bool OUT_IS_F32>
__global__ __launch_bounds__(256) void gemm_bt(
    const void* __restrict__ Ap,
    const float* __restrict__ Wa, const float* __restrict__ Wb, const float* __restrict__ Wc,
    const float* __restrict__ Ba, const float* __restrict__ Bb, const float* __restrict__ Bc,
    void* __restrict__ Oa, void* __restrict__ Ob, void* __restrict__ Oc,
    int ntiles)
{
    __shared__ unsigned short lA[128*64];
    __shared__ unsigned short lW[128*64];
    const int bid = blockIdx.x;
    const int nt = bid % ntiles;      // nt-major: A-tile reuse is temporally local
    const int mt = bid / ntiles;
    const int mat = nt / 3;
    const int ncol = nt - mat*3;
    const float* Wsel = (mat==0) ? Wa : ((mat==1) ? Wb : Wc);
    const float* Bsel = (mat==0) ? Ba : ((mat==1) ? Bb : Bc);
    void* Osel        = (mat==0) ? Oa : ((mat==1) ? Ob : Oc);
    const int Mbase = mt*128, Nbase = ncol*128;
    const int t = threadIdx.x;
    const int w = t >> 6, l = t & 63;
    const int wr = w >> 1, wc = w & 1;
    const int lr = l & 15, lg = l >> 4;

    f32x4 acc[4][4] = {};
    for (int kt = 0; kt < 6; ++kt) {
        __syncthreads();
        #pragma unroll
        for (int i = 0; i < 4; ++i) {
            int c = i*256 + t;
            int row = c >> 3, c8 = c & 7;
            size_t asrc = (size_t)(Mbase+row)*NC + kt*64 + c8*8;
            if (A_IS_F32) {
                const float* Af = (const float*)Ap;
                f32x4 a0 = *(const f32x4*)&Af[asrc];
                f32x4 a1 = *(const f32x4*)&Af[asrc + 4];
                u16x8 pk;
                #pragma unroll
                for (int j = 0; j < 4; ++j) { pk[j] = f2bf(a0[j]); pk[j+4] = f2bf(a1[j]); }
                *(u16x8*)&lA[c*8] = pk;
            } else {
                *(u16x8*)&lA[c*8] = *(const u16x8*)&((const unsigned short*)Ap)[asrc];
            }
            size_t wsrc = (size_t)(Nbase+row)*NC + kt*64 + c8*8;
            f32x4 w0 = *(const f32x4*)&Wsel[wsrc];
            f32x4 w1 = *(const f32x4*)&Wsel[wsrc + 4];
            u16x8 wk;
            #pragma unroll
            for (int j = 0; j < 4; ++j) { wk[j] = f2bf(w0[j]); wk[j+4] = f2bf(w1[j]); }
            *(u16x8*)&lW[c*8] = wk;
        }
        __syncthreads();
        #pragma unroll
        for (int kk = 0; kk < 2; ++kk) {
            s16x8 af[4], bfr[4];
            #pragma unroll
            for (int m = 0; m < 4; ++m)
                af[m] = *(const s16x8*)&lA[(wr*64 + m*16 + lr)*64 + kk*32 + lg*8];
            #pragma unroll
            for (int n = 0; n < 4; ++n)
                bfr[n] = *(const s16x8*)&lW[(wc*64 + n*16 + lr)*64 + kk*32 + lg*8];
            #pragma unroll
            for (int m = 0; m < 4; ++m)
                #pragma unroll
                for (int n = 0; n < 4; ++n)
                    acc[m][n] = __builtin_amdgcn_mfma_f32_16x16x32_bf16(af[m], bfr[n], acc[m][n], 0, 0, 0);
        }
    }
    #pragma unroll
    for (int n = 0; n < 4; ++n) {
        int col = Nbase + wc*64 + n*16 + lr;
        float bias = Bsel[col];
        #pragma unroll
        for (int m = 0; m < 4; ++m) {
            int row0 = Mbase + wr*64 + m*16 + lg*4;
            #pragma unroll
            for (int r = 0; r < 4; ++r) {
                float vv = acc[m][n][r] + bias;
                if (OUT_IS_F32) ((float*)Osel)[(size_t)(row0 + r)*NC + col] = vv;
                else ((unsigned short*)Osel)[(size_t)(row0 + r)*NC + col] = f2bf(vv);
            }
        }
    }
}

// Depthwise 3x3 conv, pad 1, stride S, token layout (NB, 56*56, NC) -> (NB, HO*WO, NC)
// input bf16, transposed weights (9,NC) f32, bias f32, output bf16.
// SCALE: multiply output by 0.125 (folds attention's 1/sqrt(64) into Q).
// TRANS: write transposed layout Vt[(b*6+h)*64 + d][tok] for attention's V^T operand.
template<int S, int HO, int WO, bool SCALE, bool TRANS>
__global__ __launch_bounds__(256) void dwconv(
    const unsigned short* __restrict__ in,
    const float* __restrict__ wt9,   // (9, NC) transposed
    const float* __restrict__ bias,  // (NC)
    unsigned short* __restrict__ outp)
{
    const int nc8 = NC/8;
    int idx = blockIdx.x*256 + threadIdx.x;
    if (idx >= NB*HO*WO*nc8) return;
    int c8 = idx % nc8; int rest = idx / nc8;
    int wo = rest % WO; rest /= WO;
    int ho = rest % HO; int b = rest / HO;
    int c0 = c8*8;
    f32x4 b0 = *(const f32x4*)&bias[c0];
    f32x4 b1 = *(const f32x4*)&bias[c0+4];
    float acc[8];
    #pragma unroll
    for (int j = 0; j < 4; ++j) { acc[j] = b0[j]; acc[j+4] = b1[j]; }
    #pragma unroll
    for (int kh = 0; kh < 3; ++kh) {
        int h = ho*S + kh - 1;
        if (h < 0 || h >= HH) continue;
        #pragma unroll
        for (int kw = 0; kw < 3; ++kw) {
            int ww = wo*S + kw - 1;
            if (ww < 0 || ww >= WW0) continue;
            int tap = kh*3 + kw;
            u16x8 xv = *(const u16x8*)&in[((size_t)b*(HH*WW0) + h*WW0 + ww)*NC + c0];
            f32x4 w0 = *(const f32x4*)&wt9[tap*NC + c0];
            f32x4 w1 = *(const f32x4*)&wt9[tap*NC + c0 + 4];
            #pragma unroll
            for (int j = 0; j < 4; ++j) {
                acc[j]   += bf2f(xv[j])   * w0[j];
                acc[j+4] += bf2f(xv[j+4]) * w1[j];
            }
        }
    }
    if (SCALE) {
        #pragma unroll
        for (int j = 0; j < 8; ++j) acc[j] *= 0.125f;
    }
    int tok = ho*WO + wo;
    if (TRANS) {
        int hh = c0 >> 6, d0 = c0 & 63;
        size_t base = ((size_t)(b*NHEAD + hh)*HDIM + d0)*(HO*WO) + tok;
        #pragma unroll
        for (int j = 0; j < 8; ++j)
            outp[base + (size_t)j*(HO*WO)] = f2bf(acc[j]);
    } else {
        u16x8 ov;
        #pragma unroll
        for (int j = 0; j < 8; ++j) ov[j] = f2bf(acc[j]);
        *(u16x8*)&outp[((size_t)b*(HO*WO) + tok)*NC + c0] = ov;
    }
}

// Flash-style attention, sign(s)*softmax(|s|), Q pre-scaled by 1/8.
// Per wave: 32 q rows (2 x 16-row fragments), KVBLK=64, no LDS, no barriers.
// S^T = mfma16x16x32(K_frag, Q_frag): lane holds S[k=kbase+kfr*16+lg*4+r][q=q0+lq].
// S^T D-layout == B-operand layout of mfma_16x16x16bf16_1k -> P feeds PV with zero shuffles.
// V^T A-fragments come as single 8B loads from the pre-transposed Vt[b,h,d,k].
__global__ __launch_bounds__(256) void attn_fwd(
    const unsigned short* __restrict__ Q,   // (NB, 3136, 384) bf16, pre-scaled
    const unsigned short* __restrict__ K,   // (NB, 784, 384) bf16
    const unsigned short* __restrict__ Vt,  // (NB*6, 64, 784) bf16 transposed
    unsigned short* __restrict__ ctx)       // (NB, 3136, 384) bf16
{
    const int bid = blockIdx.x;
    const int qt = bid % 25;
    const int bh = bid / 25;
    const int b = bh / NHEAD, h = bh - b*NHEAD;
    const int t = threadIdx.x;
    const int w = t >> 6, l = t & 63;
    const int lq = l & 15, lg = l >> 4;
    const int wq0 = qt*128 + w*32;
    if (wq0 >= NQTOK) return;

    const unsigned short* Qb = Q + ((size_t)b*NQTOK + wq0 + lq)*NC + h*HDIM;
    s16x8 qA[2][2];
    qA[0][0] = *(const s16x8*)&Qb[lg*8];
    qA[0][1] = *(const s16x8*)&Qb[32 + lg*8];
    qA[1][0] = *(const s16x8*)&Qb[16*NC + lg*8];
    qA[1][1] = *(const s16x8*)&Qb[16*NC + 32 + lg*8];

    const unsigned short* Kb = K + (size_t)b*NKTOK*NC + h*HDIM;
    const unsigned short* Vb = Vt + (size_t)bh*HDIM*NKTOK;

    float mrun[2] = {0.f, 0.f}, lrun[2] = {0.f, 0.f};
    f32x4 oacc[2][4] = {};

    for (int kt = 0; kt < 12; ++kt) {
        const int kbase = kt*64;
        f32x4 st[2][4] = {};
        #pragma unroll
        for (int kfr = 0; kfr < 4; ++kfr) {
            const unsigned short* kr = &Kb[(size_t)(kbase + kfr*16 + lq)*NC];
            s16x8 kf0 = *(const s16x8*)&kr[lg*8];
            s16x8 kf1 = *(const s16x8*)&kr[32 + lg*8];
            st[0][kfr] = __builtin_amdgcn_mfma_f32_16x16x32_bf16(kf0, qA[0][0], st[0][kfr], 0,0,0);
            st[0][kfr] = __builtin_amdgcn_mfma_f32_16x16x32_bf16(kf1, qA[0][1], st[0][kfr], 0,0,0);
            st[1][kfr] = __builtin_amdgcn_mfma_f32_16x16x32_bf16(kf0, qA[1][0], st[1][kfr], 0,0,0);
            st[1][kfr] = __builtin_amdgcn_mfma_f32_16x16x32_bf16(kf1, qA[1][1], st[1][kfr], 0,0,0);
        }
        // V^T fragments (shared by both q-fragments); independent of S -> issued early
        s16x4 vv[4][4];
        #pragma unroll
        for (int ks = 0; ks < 4; ++ks)
            #pragma unroll
            for (int f = 0; f < 4; ++f)
                vv[ks][f] = *(const s16x4*)&Vb[(size_t)(f*16 + lq)*NKTOK + kbase + ks*16 + lg*4];
        // online signed softmax in log2 domain
        s16x4 pbv[2][4];
        #pragma unroll
        for (int qf = 0; qf < 2; ++qf) {
            float av[4][4], tm = 0.f;
            #pragma unroll
            for (int kfr = 0; kfr < 4; ++kfr)
                #pragma unroll
                for (int r = 0; r < 4; ++r) {
                    av[kfr][r] = LOG2E * fabsf(st[qf][kfr][r]);
                    tm = fmaxf(tm, av[kfr][r]);
                }
            tm = fmaxf(tm, __shfl_xor(tm, 16));
            tm = fmaxf(tm, __shfl_xor(tm, 32));
            if (!__all(tm <= mrun[qf] + 11.5416f)) {   // defer-max, THR = 8*log2e
                float mnew = fmaxf(mrun[qf], tm);
                float corr = exp2f(mrun[qf] - mnew);
                #pragma unroll
                for (int f = 0; f < 4; ++f)
                    #pragma unroll
                    for (int r = 0; r < 4; ++r) oacc[qf][f][r] *= corr;
                lrun[qf] *= corr;
                mrun[qf] = mnew;
            }
            float rs = 0.f;
            #pragma unroll
            for (int kfr = 0; kfr < 4; ++kfr)
                #pragma unroll
                for (int r = 0; r < 4; ++r) {
                    float e = exp2f(av[kfr][r] - mrun[qf]);
                    rs += e;
                    pbv[qf][kfr][r] = f2bf_hw(copysignf(e, st[qf][kfr][r]));
                }
            rs += __shfl_xor(rs, 16);
            rs += __shfl_xor(rs, 32);
            lrun[qf] += rs;
        }
        // PV
        #pragma unroll
        for (int ks = 0; ks < 4; ++ks)
            #pragma unroll
            for (int f = 0; f < 4; ++f) {
                oacc[0][f] = __builtin_amdgcn_mfma_f32_16x16x16bf16_1k(vv[ks][f], pbv[0][ks], oacc[0][f], 0,0,0);
                oacc[1][f] = __builtin_amdgcn_mfma_f32_16x16x16bf16_1k(vv[ks][f], pbv[1][ks], oacc[1][f], 0,0,0);
            }
    }
    // tail: k = 768..783 (16 rows, exactly one fragment)
    {
        const int kbase = 768;
        const unsigned short* kr = &Kb[(size_t)(kbase + lq)*NC];
        s16x8 kf0 = *(const s16x8*)&kr[lg*8];
        s16x8 kf1 = *(const s16x8*)&kr[32 + lg*8];
        f32x4 st[2] = {};
        st[0] = __builtin_amdgcn_mfma_f32_16x16x32_bf16(kf0, qA[0][0], st[0], 0,0,0);
        st[0] = __builtin_amdgcn_mfma_f32_16x16x32_bf16(kf1, qA[0][1], st[0], 0,0,0);
        st[1] = __builtin_amdgcn_mfma_f32_16x16x32_bf16(kf0, qA[1][0], st[1], 0,0,0);
        st[1] = __builtin_amdgcn_mfma_f32_16x16x32_bf16(kf1, qA[1][1], st[1], 0,0,0);
        s16x4 vv[4];
        #pragma unroll
        for (int f = 0; f < 4; ++f)
            vv[f] = *(const s16x4*)&Vb[(size_t)(f*16 + lq)*NKTOK + kbase + lg*4];
        s16x4 pbv[2];
        #pragma unroll
        for (int qf = 0; qf < 2; ++qf) {
            float av[4], tm = 0.f;
            #pragma unroll
            for (int r = 0; r < 4; ++r) { av[r] = LOG2E * fabsf(st[qf][r]); tm = fmaxf(tm, av[r]); }
            tm = fmaxf(tm, __shfl_xor(tm, 16));
            tm = fmaxf(tm, __shfl_xor(tm, 32));
            if (!__all(tm <= mrun[qf] + 11.5416f)) {
                float mnew = fmaxf(mrun[qf], tm);
                float corr = exp2f(mrun[qf] - mnew);
                #pragma unroll
                for (int f = 0; f < 4; ++f)
                    #pragma unroll
                    for (int r = 0; r < 4; ++r) oacc[qf][f][r] *= corr;
                lrun[qf] *= corr;
                mrun[qf] = mnew;
            }
            float rs = 0.f;
            #pragma unroll
            for (int r = 0; r < 4; ++r) {
                float e = exp2f(av[r] - mrun[qf]);
                rs += e;
                pbv[qf][r] = f2bf_hw(copysignf(e, st[qf][r]));
            }
            rs += __shfl_xor(rs, 16);
            rs += __shfl_xor(rs, 32);
            lrun[qf] += rs;
        }
        #pragma unroll
        for (int f = 0; f < 4; ++f) {
            oacc[0][f] = __builtin_amdgcn_mfma_f32_16x16x16bf16_1k(vv[f], pbv[0], oacc[0][f], 0,0,0);
            oacc[1][f] = __builtin_amdgcn_mfma_f32_16x16x16bf16_1k(vv[f], pbv[1], oacc[1][f], 0,0,0);
        }
    }
    // store
    #pragma unroll
    for (int qf = 0; qf < 2; ++qf) {
        float inv = 1.f / lrun[qf];
        unsigned short* cb = ctx + ((size_t)b*NQTOK + wq0 + qf*16 + lq)*NC + h*HDIM;
        #pragma unroll
        for (int f = 0; f < 4; ++f) {
            s16x4 o;
            #pragma unroll
            for (int r = 0; r < 4; ++r) o[r] = (short)f2bf(oacc[qf][f][r] * inv);
            *(s16x4*)&cb[f*16 + lg*4] = o;
        }
    }
}

extern "C" void kernel_launch(void* const* d_in, const int* in_sizes, int n_in,
                              void* d_out, int out_size, void* d_ws, size_t ws_size,
                              hipStream_t stream)
{
    (void)in_sizes; (void)n_in; (void)out_size; (void)ws_size;
    const float* x      = (const float*)d_in[0];
    const float* q_w    = (const float*)d_in[3];
    const float* q_b    = (const float*)d_in[4];
    const float* k_w    = (const float*)d_in[5];
    const float* k_b    = (const float*)d_in[6];
    const float* v_w    = (const float*)d_in[7];
    const float* v_b    = (const float*)d_in[8];
    const float* q_dw_w = (const float*)d_in[9];
    const float* q_dw_b = (const float*)d_in[10];
    const float* k_dw_w = (const float*)d_in[11];
    const float* k_dw_b = (const float*)d_in[12];
    const float* v_dw_w = (const float*)d_in[13];
    const float* v_dw_b = (const float*)d_in[14];
    const float* proj_w = (const float*)d_in[15];
    const float* proj_b = (const float*)d_in[16];
    float* outf = (float*)d_out;
    unsigned short* ws  = (unsigned short*)d_ws;

    const size_t nQ  = (size_t)NB*NQTOK*NC;   // 9,633,792 elems
    const size_t nKc = (size_t)NB*NKTOK*NC;   // 2,408,448 elems
    unsigned short* preQ = ws;                // bf16 pre-conv Q
    unsigned short* preK = ws + nQ;           // bf16 pre-conv K; later ctx
    unsigned short* Kc   = ws + 2*nQ;         // bf16 post-conv K
    unsigned short* Vt   = Kc + nKc;          // bf16 post-conv V, TRANSPOSED (b,h,d,k)
    unsigned short* preV = (unsigned short*)d_out;  // bf16 pre-conv V (d_out lower half)
    unsigned short* Qc   = (unsigned short*)d_out;  // bf16 post-conv Q (after preV consumed)
    unsigned short* ctx  = preK;              // reuse preK space after conv_k
    float* wtab = (float*)(((unsigned short*)d_out) + nQ);  // d_out upper half: [3][9][NC] f32

    // 0. transpose dw weights for coalesced conv loads
    prep_w<<<dim3(41), dim3(256), 0, stream>>>(q_dw_w, k_dw_w, v_dw_w, wtab);
    // 1. QKV projections: x(f32) @ W^T -> bf16 Q,K,V
    gemm_bt<true,false><<<dim3(196*9), dim3(256), 0, stream>>>(
        x, q_w, k_w, v_w, q_b, k_b, v_b, preQ, preK, preV, 9);
    // 2. depthwise convs; K normal, V transposed, Q scaled by 1/8
    dwconv<2,28,28,false,false><<<dim3(1176), dim3(256), 0, stream>>>(preK, wtab + 1*9*NC, k_dw_b, Kc);
    dwconv<2,28,28,false,true ><<<dim3(1176), dim3(256), 0, stream>>>(preV, wtab + 2*9*NC, v_dw_b, Vt);
    dwconv<1,56,56,true ,false><<<dim3(4704), dim3(256), 0, stream>>>(preQ, wtab + 0*9*NC, q_dw_b, Qc);
    // 3. attention: 48 bh x 25 q-tiles of 128
    attn_fwd<<<dim3(1200), dim3(256), 0, stream>>>(Qc, Kc, Vt, ctx);
    // 4. output projection: ctx(bf16) @ proj_w^T + proj_b -> f32 d_out
    gemm_bt<false,true><<<dim3(196*3), dim3(256), 0, stream>>>(
        ctx, proj_w, proj_w, proj_w, proj_b, proj_b, proj_b, outf, outf, outf, 3);
}

// Round 5
// 239.510 us; speedup vs baseline: 2.1225x; 1.0726x over previous
//
#include <hip/hip_runtime.h>
#include <hip/hip_bf16.h>
#include <stdint.h>

typedef __attribute__((ext_vector_type(4))) float f32x4;
typedef __attribute__((ext_vector_type(8))) short s16x8;
typedef __attribute__((ext_vector_type(4))) short s16x4;
typedef __attribute__((ext_vector_type(8))) unsigned short u16x8;

#define NB 8
#define HH 56
#define WW0 56
#define NC 384
#define NQTOK (HH*WW0)     // 3136
#define NKTOK 784
#define NHEAD 6
#define HDIM 64
// scale folded into q-conv: (1/sqrt(64)) * log2(e)
#define QSCALE 0.18033688f

__device__ __forceinline__ float bf2f(unsigned short u) {
    union { unsigned int i; float f; } x; x.i = ((unsigned int)u) << 16; return x.f;
}
__device__ __forceinline__ unsigned short f2bf(float f) {
    union { float f; unsigned int i; } x; x.f = f;
    unsigned int r = x.i + 0x7FFFu + ((x.i >> 16) & 1u);
    return (unsigned short)(r >> 16);
}
__device__ __forceinline__ short f2bf_hw(float f) {
    __hip_bfloat16 hb = __float2bfloat16(f);
    return *reinterpret_cast<short*>(&hb);
}

// ---------- prep kernels ----------
__global__ __launch_bounds__(256) void cvt_bf16(const float* __restrict__ src,
                                                unsigned short* __restrict__ dst, int n8) {
    int i = blockIdx.x*256 + threadIdx.x;
    if (i >= n8) return;
    f32x4 a0 = *(const f32x4*)&src[(size_t)i*8];
    f32x4 a1 = *(const f32x4*)&src[(size_t)i*8 + 4];
    u16x8 p;
    #pragma unroll
    for (int j = 0; j < 4; ++j) { p[j] = f2bf(a0[j]); p[j+4] = f2bf(a1[j]); }
    *(u16x8*)&dst[(size_t)i*8] = p;
}

// 4 dense weight matrices f32 -> bf16, concatenated [4][384*384]
__global__ __launch_bounds__(256) void cvt_w4(
    const float* __restrict__ a, const float* __restrict__ b,
    const float* __restrict__ c, const float* __restrict__ d,
    unsigned short* __restrict__ dst) {
    int i = blockIdx.x*256 + threadIdx.x;              // 73728 = 4*147456/8
    if (i >= 73728) return;
    int m = i / 18432;
    const float* s = (m==0) ? a : ((m==1) ? b : ((m==2) ? c : d));
    int r = i - m*18432;
    f32x4 a0 = *(const f32x4*)&s[(size_t)r*8];
    f32x4 a1 = *(const f32x4*)&s[(size_t)r*8 + 4];
    u16x8 p;
    #pragma unroll
    for (int j = 0; j < 4; ++j) { p[j] = f2bf(a0[j]); p[j+4] = f2bf(a1[j]); }
    *(u16x8*)&dst[(size_t)i*8] = p;
}

// gather 4 biases into [4][384] f32
__global__ __launch_bounds__(256) void cvt_bias(
    const float* __restrict__ a, const float* __restrict__ b,
    const float* __restrict__ c, const float* __restrict__ d,
    float* __restrict__ dst) {
    int i = blockIdx.x*256 + threadIdx.x;
    if (i >= 4*NC) return;
    int m = i / NC, r = i - m*NC;
    dst[i] = ((m==0) ? a : ((m==1) ? b : ((m==2) ? c : d)))[r];
}

// Transpose dw weights (NC,9) -> (9,NC)
__global__ __launch_bounds__(256) void prep_w(
    const float* __restrict__ qw, const float* __restrict__ kw, const float* __restrict__ vw,
    float* __restrict__ wt)   // [3][9][NC]
{
    int i = blockIdx.x*256 + threadIdx.x;
    if (i >= 3*9*NC) return;
    int m = i / (9*NC); int r = i - m*(9*NC);
    int tap = r / NC; int c = r - tap*NC;
    const float* src = (m==0) ? qw : ((m==1) ? kw : vw);
    wt[i] = src[c*9 + tap];
}

// ---------- GEMM (pure bf16 operands) ----------
// C[m,o] = sum_k A[m,k]*W[o,k] + bias[o]; tile 128x128, BK=64, 4 waves (2x2).
template<bool OUT_F32>
__global__ __launch_bounds__(256) void gemm_bt_bf(
    const unsigned short* __restrict__ A,
    const unsigned short* __restrict__ Wall,  // [nmat][384*384] bf16
    const float* __restrict__ Ball,           // [nmat][384] f32
    unsigned short* __restrict__ Oa, unsigned short* __restrict__ Ob, unsigned short* __restrict__ Oc,
    float* __restrict__ Of,
    int ntiles)
{
    __shared__ unsigned short lA[128*64];
    __shared__ unsigned short lW[128*64];
    const int bid = blockIdx.x;
    const int nt = bid % ntiles;      // nt-major: A-tile reuse temporally local
    const int mt = bid / ntiles;
    const int mat = nt / 3;
    const int ncol = nt - mat*3;
    const unsigned short* W = Wall + (size_t)mat*NC*NC;
    const float* Bsel = Ball + mat*NC;
    unsigned short* Osel = (mat==0) ? Oa : ((mat==1) ? Ob : Oc);
    const int Mbase = mt*128, Nbase = ncol*128;
    const int t = threadIdx.x;
    const int w = t >> 6, l = t & 63;
    const int wr = w >> 1, wc = w & 1;
    const int lr = l & 15, lg = l >> 4;

    f32x4 acc[4][4] = {};
    for (int kt = 0; kt < 6; ++kt) {
        __syncthreads();
        #pragma unroll
        for (int i = 0; i < 4; ++i) {
            int c = i*256 + t;
            int row = c >> 3, c8 = c & 7;
            *(u16x8*)&lA[c*8] = *(const u16x8*)&A[(size_t)(Mbase+row)*NC + kt*64 + c8*8];
            *(u16x8*)&lW[c*8] = *(const u16x8*)&W[(size_t)(Nbase+row)*NC + kt*64 + c8*8];
        }
        __syncthreads();
        #pragma unroll
        for (int kk = 0; kk < 2; ++kk) {
            s16x8 af[4], bfr[4];
            #pragma unroll
            for (int m = 0; m < 4; ++m)
                af[m] = *(const s16x8*)&lA[(wr*64 + m*16 + lr)*64 + kk*32 + lg*8];
            #pragma unroll
            for (int n = 0; n < 4; ++n)
                bfr[n] = *(const s16x8*)&lW[(wc*64 + n*16 + lr)*64 + kk*32 + lg*8];
            #pragma unroll
            for (int m = 0; m < 4; ++m)
                #pragma unroll
                for (int n = 0; n < 4; ++n)
                    acc[m][n] = __builtin_amdgcn_mfma_f32_16x16x32_bf16(af[m], bfr[n], acc[m][n], 0, 0, 0);
        }
    }
    #pragma unroll
    for (int n = 0; n < 4; ++n) {
        int col = Nbase + wc*64 + n*16 + lr;
        float bias = Bsel[col];
        #pragma unroll
        for (int m = 0; m < 4; ++m) {
            int row0 = Mbase + wr*64 + m*16 + lg*4;
            #pragma unroll
            for (int r = 0; r < 4; ++r) {
                float vv = acc[m][n][r] + bias;
                if (OUT_F32) Of[(size_t)(row0 + r)*NC + col] = vv;
                else Osel[(size_t)(row0 + r)*NC + col] = f2bf(vv);
            }
        }
    }
}

// ---------- depthwise conv ----------
// MODE: 0 = token layout (b,tok,384); 1 = head-packed K (bh,tok,64); 2 = transposed V (bh,d,tok)
template<int S, int HO, int WO, bool SCALE, int MODE>
__global__ __launch_bounds__(256) void dwconv(
    const unsigned short* __restrict__ in,
    const float* __restrict__ wt9,   // (9, NC) transposed
    const float* __restrict__ bias,  // (NC)
    unsigned short* __restrict__ outp)
{
    const int nc8 = NC/8;
    int idx = blockIdx.x*256 + threadIdx.x;
    if (idx >= NB*HO*WO*nc8) return;
    int c8 = idx % nc8; int rest = idx / nc8;
    int wo = rest % WO; rest /= WO;
    int ho = rest % HO; int b = rest / HO;
    int c0 = c8*8;
    f32x4 b0 = *(const f32x4*)&bias[c0];
    f32x4 b1 = *(const f32x4*)&bias[c0+4];
    float acc[8];
    #pragma unroll
    for (int j = 0; j < 4; ++j) { acc[j] = b0[j]; acc[j+4] = b1[j]; }
    #pragma unroll
    for (int kh = 0; kh < 3; ++kh) {
        int h = ho*S + kh - 1;
        if (h < 0 || h >= HH) continue;
        #pragma unroll
        for (int kw = 0; kw < 3; ++kw) {
            int ww = wo*S + kw - 1;
            if (ww < 0 || ww >= WW0) continue;
            int tap = kh*3 + kw;
            u16x8 xv = *(const u16x8*)&in[((size_t)b*(HH*WW0) + h*WW0 + ww)*NC + c0];
            f32x4 w0 = *(const f32x4*)&wt9[tap*NC + c0];
            f32x4 w1 = *(const f32x4*)&wt9[tap*NC + c0 + 4];
            #pragma unroll
            for (int j = 0; j < 4; ++j) {
                acc[j]   += bf2f(xv[j])   * w0[j];
                acc[j+4] += bf2f(xv[j+4]) * w1[j];
            }
        }
    }
    if (SCALE) {
        #pragma unroll
        for (int j = 0; j < 8; ++j) acc[j] *= QSCALE;
    }
    int tok = ho*WO + wo;
    int hh = c0 >> 6, d0 = c0 & 63;
    if (MODE == 0) {
        u16x8 ov;
        #pragma unroll
        for (int j = 0; j < 8; ++j) ov[j] = f2bf(acc[j]);
        *(u16x8*)&outp[((size_t)b*(HO*WO) + tok)*NC + c0] = ov;
    } else if (MODE == 1) {
        u16x8 ov;
        #pragma unroll
        for (int j = 0; j < 8; ++j) ov[j] = f2bf(acc[j]);
        *(u16x8*)&outp[((size_t)(b*NHEAD + hh)*(HO*WO) + tok)*HDIM + d0] = ov;
    } else {
        size_t base = ((size_t)(b*NHEAD + hh)*HDIM + d0)*(HO*WO) + tok;
        #pragma unroll
        for (int j = 0; j < 8; ++j)
            outp[base + (size_t)j*(HO*WO)] = f2bf(acc[j]);
    }
}

// ---------- attention ----------
// sign(s)*softmax(|s|) with NO max tracking (shift-invariant; |s| small, e^|s| safe in f32),
// per-lane deferred denominator. Q pre-scaled by 0.125*log2e so P = exp2(|st|).
// Per wave: 32 q rows, KVBLK=64, no LDS/barriers. XCD-affinity: bid%8 selects XCD,
// 6 bh per XCD -> K+V (1.2 MB) stays in that XCD's L2.
__global__ __launch_bounds__(256) void attn_fwd(
    const unsigned short* __restrict__ Q,   // (NB, 3136, 384) bf16 pre-scaled
    const unsigned short* __restrict__ Kpk, // (NB*6, 784, 64) bf16 head-packed
    const unsigned short* __restrict__ Vt,  // (NB*6, 64, 784) bf16 transposed
    unsigned short* __restrict__ ctx)       // (NB, 3136, 384) bf16
{
    const int bid = blockIdx.x;             // 1200 = 8 XCD * 150
    const int xcd = bid & 7, slot = bid >> 3;
    const int bh = xcd*6 + slot/25;
    const int qt = slot % 25;
    const int b = bh / NHEAD, h = bh - b*NHEAD;
    const int t = threadIdx.x;
    const int w = t >> 6, l = t & 63;
    const int lq = l & 15, lg = l >> 4;
    const int wq0 = qt*128 + w*32;
    if (wq0 >= NQTOK) return;

    const unsigned short* Qb = Q + ((size_t)b*NQTOK + wq0 + lq)*NC + h*HDIM;
    s16x8 qA[2][2];
    qA[0][0] = *(const s16x8*)&Qb[lg*8];
    qA[0][1] = *(const s16x8*)&Qb[32 + lg*8];
    qA[1][0] = *(const s16x8*)&Qb[16*NC + lg*8];
    qA[1][1] = *(const s16x8*)&Qb[16*NC + 32 + lg*8];

    const unsigned short* Kb = Kpk + (size_t)bh*NKTOK*HDIM;
    const unsigned short* Vb = Vt + (size_t)bh*HDIM*NKTOK;

    float ls[2] = {0.f, 0.f};
    f32x4 oacc[2][4] = {};

    for (int kt = 0; kt < 12; ++kt) {
        const int kbase = kt*64;
        f32x4 st[2][4] = {};
        #pragma unroll
        for (int kfr = 0; kfr < 4; ++kfr) {
            const unsigned short* kr = &Kb[(size_t)(kbase + kfr*16 + lq)*HDIM];
            s16x8 kf0 = *(const s16x8*)&kr[lg*8];
            s16x8 kf1 = *(const s16x8*)&kr[32 + lg*8];
            st[0][kfr] = __builtin_amdgcn_mfma_f32_16x16x32_bf16(kf0, qA[0][0], st[0][kfr], 0,0,0);
            st[0][kfr] = __builtin_amdgcn_mfma_f32_16x16x32_bf16(kf1, qA[0][1], st[0][kfr], 0,0,0);
            st[1][kfr] = __builtin_amdgcn_mfma_f32_16x16x32_bf16(kf0, qA[1][0], st[1][kfr], 0,0,0);
            st[1][kfr] = __builtin_amdgcn_mfma_f32_16x16x32_bf16(kf1, qA[1][1], st[1][kfr], 0,0,0);
        }
        s16x4 vv[4][4];
        #pragma unroll
        for (int ks = 0; ks < 4; ++ks)
            #pragma unroll
            for (int f = 0; f < 4; ++f)
                vv[ks][f] = *(const s16x4*)&Vb[(size_t)(f*16 + lq)*NKTOK + kbase + ks*16 + lg*4];
        s16x4 pbv[2][4];
        #pragma unroll
        for (int qf = 0; qf < 2; ++qf) {
            float rs = 0.f;
            #pragma unroll
            for (int kfr = 0; kfr < 4; ++kfr)
                #pragma unroll
                for (int r = 0; r < 4; ++r) {
                    float s = st[qf][kfr][r];
                    float e = exp2f(fabsf(s));
                    rs += e;
                    pbv[qf][kfr][r] = f2bf_hw(copysignf(e, s));
                }
            ls[qf] += rs;
        }
        #pragma unroll
        for (int ks = 0; ks < 4; ++ks)
            #pragma unroll
            for (int f = 0; f < 4; ++f) {
                oacc[0][f] = __builtin_amdgcn_mfma_f32_16x16x16bf16_1k(vv[ks][f], pbv[0][ks], oacc[0][f], 0,0,0);
                oacc[1][f] = __builtin_amdgcn_mfma_f32_16x16x16bf16_1k(vv[ks][f], pbv[1][ks], oacc[1][f], 0,0,0);
            }
    }
    // tail: k = 768..783
    {
        const int kbase = 768;
        const unsigned short* kr = &Kb[(size_t)(kbase + lq)*HDIM];
        s16x8 kf0 = *(const s16x8*)&kr[lg*8];
        s16x8 kf1 = *(const s16x8*)&kr[32 + lg*8];
        f32x4 st[2] = {};
        st[0] = __builtin_amdgcn_mfma_f32_16x16x32_bf16(kf0, qA[0][0], st[0], 0,0,0);
        st[0] = __builtin_amdgcn_mfma_f32_16x16x32_bf16(kf1, qA[0][1], st[0], 0,0,0);
        st[1] = __builtin_amdgcn_mfma_f32_16x16x32_bf16(kf0, qA[1][0], st[1], 0,0,0);
        st[1] = __builtin_amdgcn_mfma_f32_16x16x32_bf16(kf1, qA[1][1], st[1], 0,0,0);
        s16x4 vv[4];
        #pragma unroll
        for (int f = 0; f < 4; ++f)
            vv[f] = *(const s16x4*)&Vb[(size_t)(f*16 + lq)*NKTOK + kbase + lg*4];
        s16x4 pbv[2];
        #pragma unroll
        for (int qf = 0; qf < 2; ++qf) {
            float rs = 0.f;
            #pragma unroll
            for (int r = 0; r < 4; ++r) {
                float s = st[qf][r];
                float e = exp2f(fabsf(s));
                rs += e;
                pbv[qf][r] = f2bf_hw(copysignf(e, s));
            }
            ls[qf] += rs;
        }
        #pragma unroll
        for (int f = 0; f < 4; ++f) {
            oacc[0][f] = __builtin_amdgcn_mfma_f32_16x16x16bf16_1k(vv[f], pbv[0], oacc[0][f], 0,0,0);
            oacc[1][f] = __builtin_amdgcn_mfma_f32_16x16x16bf16_1k(vv[f], pbv[1], oacc[1][f], 0,0,0);
        }
    }
    // single deferred reduction + store
    #pragma unroll
    for (int qf = 0; qf < 2; ++qf) {
        float lr2 = ls[qf];
        lr2 += __shfl_xor(lr2, 16);
        lr2 += __shfl_xor(lr2, 32);
        float inv = 1.f / lr2;
        unsigned short* cb = ctx + ((size_t)b*NQTOK + wq0 + qf*16 + lq)*NC + h*HDIM;
        #pragma unroll
        for (int f = 0; f < 4; ++f) {
            s16x4 o;
            #pragma unroll
            for (int r = 0; r < 4; ++r) o[r] = (short)f2bf(oacc[qf][f][r] * inv);
            *(s16x4*)&cb[f*16 + lg*4] = o;
        }
    }
}

extern "C" void kernel_launch(void* const* d_in, const int* in_sizes, int n_in,
                              void* d_out, int out_size, void* d_ws, size_t ws_size,
                              hipStream_t stream)
{
    (void)in_sizes; (void)n_in; (void)out_size; (void)ws_size;
    const float* x      = (const float*)d_in[0];
    const float* q_w    = (const float*)d_in[3];
    const float* q_b    = (const float*)d_in[4];
    const float* k_w    = (const float*)d_in[5];
    const float* k_b    = (const float*)d_in[6];
    const float* v_w    = (const float*)d_in[7];
    const float* v_b    = (const float*)d_in[8];
    const float* q_dw_w = (const float*)d_in[9];
    const float* q_dw_b = (const float*)d_in[10];
    const float* k_dw_w = (const float*)d_in[11];
    const float* k_dw_b = (const float*)d_in[12];
    const float* v_dw_w = (const float*)d_in[13];
    const float* v_dw_b = (const float*)d_in[14];
    const float* proj_w = (const float*)d_in[15];
    const float* proj_b = (const float*)d_in[16];
    float* outf = (float*)d_out;
    unsigned short* ws  = (unsigned short*)d_ws;

    const size_t nQ  = (size_t)NB*NQTOK*NC;   // 9,633,792 elems
    const size_t nKc = (size_t)NB*NKTOK*NC;   // 2,408,448 elems
    unsigned short* preQ = ws;                // bf16 pre-conv Q
    unsigned short* preK = ws + nQ;           // bf16 pre-conv K; later ctx
    unsigned short* Kpk  = ws + 2*nQ;         // bf16 post-conv K, head-packed (bh,k,64)
    unsigned short* Vt   = Kpk + nKc;         // bf16 post-conv V, transposed (bh,d,k)
    unsigned short* wbf  = Vt + nKc;          // bf16 [4][384*384] dense weights
    float* wtab = (float*)(wbf + (size_t)4*NC*NC);   // [3][9][384] dw weights transposed
    float* ball = wtab + 3*9*NC;              // [4][384] biases
    unsigned short* preV = (unsigned short*)d_out;          // d_out lower half
    unsigned short* Qc   = (unsigned short*)d_out;          // after preV consumed
    unsigned short* xbf  = ((unsigned short*)d_out) + nQ;   // d_out upper half: bf16 x
    unsigned short* ctx  = preK;              // reuse preK after k-conv

    // 0. prep: dtype conversions + weight transposes
    cvt_bf16<<<dim3(4704), dim3(256), 0, stream>>>(x, xbf, (int)(nQ/8));
    cvt_w4  <<<dim3(288),  dim3(256), 0, stream>>>(q_w, k_w, v_w, proj_w, wbf);
    cvt_bias<<<dim3(6),    dim3(256), 0, stream>>>(q_b, k_b, v_b, proj_b, ball);
    prep_w  <<<dim3(41),   dim3(256), 0, stream>>>(q_dw_w, k_dw_w, v_dw_w, wtab);
    // 1. QKV projections (bf16 x bf16): Q->preQ, K->preK, V->preV(d_out)
    gemm_bt_bf<false><<<dim3(196*9), dim3(256), 0, stream>>>(
        xbf, wbf, ball, preQ, preK, preV, nullptr, 9);
    // 2. depthwise convs; K head-packed, V transposed, Q scaled by 0.125*log2e
    dwconv<2,28,28,false,1><<<dim3(1176), dim3(256), 0, stream>>>(preK, wtab + 1*9*NC, k_dw_b, Kpk);
    dwconv<2,28,28,false,2><<<dim3(1176), dim3(256), 0, stream>>>(preV, wtab + 2*9*NC, v_dw_b, Vt);
    dwconv<1,56,56,true ,0><<<dim3(4704), dim3(256), 0, stream>>>(preQ, wtab + 0*9*NC, q_dw_b, Qc);
    // 3. attention
    attn_fwd<<<dim3(1200), dim3(256), 0, stream>>>(Qc, Kpk, Vt, ctx);
    // 4. output projection -> f32 d_out
    gemm_bt_bf<true><<<dim3(196*3), dim3(256), 0, stream>>>(
        ctx, wbf + (size_t)3*NC*NC, ball + 3*NC, nullptr, nullptr, nullptr, outf, 3);
}

// Round 6
// 210.368 us; speedup vs baseline: 2.4165x; 1.1385x over previous
//
#include <hip/hip_runtime.h>
#include <hip/hip_bf16.h>
#include <stdint.h>

typedef __attribute__((ext_vector_type(4))) float f32x4;
typedef __attribute__((ext_vector_type(8))) short s16x8;
typedef __attribute__((ext_vector_type(4))) short s16x4;
typedef __attribute__((ext_vector_type(8))) unsigned short u16x8;

#define NB 8
#define HH 56
#define WW0 56
#define NC 384
#define NQTOK (HH*WW0)     // 3136
#define NKTOK 784
#define NHEAD 6
#define HDIM 64
// scale folded into q-conv: (1/sqrt(64)) * log2(e)
#define QSCALE 0.18033688f

__device__ __forceinline__ float bf2f(unsigned short u) {
    union { unsigned int i; float f; } x; x.i = ((unsigned int)u) << 16; return x.f;
}
__device__ __forceinline__ unsigned short f2bf(float f) {
    union { float f; unsigned int i; } x; x.f = f;
    unsigned int r = x.i + 0x7FFFu + ((x.i >> 16) & 1u);
    return (unsigned short)(r >> 16);
}

// ---------- prep kernels ----------
__global__ __launch_bounds__(256) void cvt_bf16(const float* __restrict__ src,
                                                unsigned short* __restrict__ dst, int n8) {
    int i = blockIdx.x*256 + threadIdx.x;
    if (i >= n8) return;
    f32x4 a0 = *(const f32x4*)&src[(size_t)i*8];
    f32x4 a1 = *(const f32x4*)&src[(size_t)i*8 + 4];
    u16x8 p;
    #pragma unroll
    for (int j = 0; j < 4; ++j) { p[j] = f2bf(a0[j]); p[j+4] = f2bf(a1[j]); }
    *(u16x8*)&dst[(size_t)i*8] = p;
}

__global__ __launch_bounds__(256) void cvt_w4(
    const float* __restrict__ a, const float* __restrict__ b,
    const float* __restrict__ c, const float* __restrict__ d,
    unsigned short* __restrict__ dst) {
    int i = blockIdx.x*256 + threadIdx.x;              // 73728 = 4*147456/8
    if (i >= 73728) return;
    int m = i / 18432;
    const float* s = (m==0) ? a : ((m==1) ? b : ((m==2) ? c : d));
    int r = i - m*18432;
    f32x4 a0 = *(const f32x4*)&s[(size_t)r*8];
    f32x4 a1 = *(const f32x4*)&s[(size_t)r*8 + 4];
    u16x8 p;
    #pragma unroll
    for (int j = 0; j < 4; ++j) { p[j] = f2bf(a0[j]); p[j+4] = f2bf(a1[j]); }
    *(u16x8*)&dst[(size_t)i*8] = p;
}

__global__ __launch_bounds__(256) void cvt_bias(
    const float* __restrict__ a, const float* __restrict__ b,
    const float* __restrict__ c, const float* __restrict__ d,
    float* __restrict__ dst) {
    int i = blockIdx.x*256 + threadIdx.x;
    if (i >= 4*NC) return;
    int m = i / NC, r = i - m*NC;
    dst[i] = ((m==0) ? a : ((m==1) ? b : ((m==2) ? c : d)))[r];
}

__global__ __launch_bounds__(256) void prep_w(
    const float* __restrict__ qw, const float* __restrict__ kw, const float* __restrict__ vw,
    float* __restrict__ wt)   // [3][9][NC]
{
    int i = blockIdx.x*256 + threadIdx.x;
    if (i >= 3*9*NC) return;
    int m = i / (9*NC); int r = i - m*(9*NC);
    int tap = r / NC; int c = r - tap*NC;
    const float* src = (m==0) ? qw : ((m==1) ? kw : vw);
    wt[i] = src[c*9 + tap];
}

// ---------- GEMM (pure bf16 operands) ----------
template<bool OUT_F32>
__global__ __launch_bounds__(256) void gemm_bt_bf(
    const unsigned short* __restrict__ A,
    const unsigned short* __restrict__ Wall,  // [nmat][384*384] bf16
    const float* __restrict__ Ball,           // [nmat][384] f32
    unsigned short* __restrict__ Oa, unsigned short* __restrict__ Ob, unsigned short* __restrict__ Oc,
    float* __restrict__ Of,
    int ntiles)
{
    __shared__ unsigned short lA[128*64];
    __shared__ unsigned short lW[128*64];
    const int bid = blockIdx.x;
    const int nt = bid % ntiles;
    const int mt = bid / ntiles;
    const int mat = nt / 3;
    const int ncol = nt - mat*3;
    const unsigned short* W = Wall + (size_t)mat*NC*NC;
    const float* Bsel = Ball + mat*NC;
    unsigned short* Osel = (mat==0) ? Oa : ((mat==1) ? Ob : Oc);
    const int Mbase = mt*128, Nbase = ncol*128;
    const int t = threadIdx.x;
    const int w = t >> 6, l = t & 63;
    const int wr = w >> 1, wc = w & 1;
    const int lr = l & 15, lg = l >> 4;

    f32x4 acc[4][4] = {};
    for (int kt = 0; kt < 6; ++kt) {
        __syncthreads();
        #pragma unroll
        for (int i = 0; i < 4; ++i) {
            int c = i*256 + t;
            int row = c >> 3, c8 = c & 7;
            *(u16x8*)&lA[c*8] = *(const u16x8*)&A[(size_t)(Mbase+row)*NC + kt*64 + c8*8];
            *(u16x8*)&lW[c*8] = *(const u16x8*)&W[(size_t)(Nbase+row)*NC + kt*64 + c8*8];
        }
        __syncthreads();
        #pragma unroll
        for (int kk = 0; kk < 2; ++kk) {
            s16x8 af[4], bfr[4];
            #pragma unroll
            for (int m = 0; m < 4; ++m)
                af[m] = *(const s16x8*)&lA[(wr*64 + m*16 + lr)*64 + kk*32 + lg*8];
            #pragma unroll
            for (int n = 0; n < 4; ++n)
                bfr[n] = *(const s16x8*)&lW[(wc*64 + n*16 + lr)*64 + kk*32 + lg*8];
            #pragma unroll
            for (int m = 0; m < 4; ++m)
                #pragma unroll
                for (int n = 0; n < 4; ++n)
                    acc[m][n] = __builtin_amdgcn_mfma_f32_16x16x32_bf16(af[m], bfr[n], acc[m][n], 0, 0, 0);
        }
    }
    #pragma unroll
    for (int n = 0; n < 4; ++n) {
        int col = Nbase + wc*64 + n*16 + lr;
        float bias = Bsel[col];
        #pragma unroll
        for (int m = 0; m < 4; ++m) {
            int row0 = Mbase + wr*64 + m*16 + lg*4;
            #pragma unroll
            for (int r = 0; r < 4; ++r) {
                float vv = acc[m][n][r] + bias;
                if (OUT_F32) Of[(size_t)(row0 + r)*NC + col] = vv;
                else Osel[(size_t)(row0 + r)*NC + col] = f2bf(vv);
            }
        }
    }
}

// ---------- depthwise conv ----------
// MODE: 0 = token layout (b,tok,384); 1 = head-packed K (bh,tok,64); 2 = transposed V (bh,d,tok)
template<int S, int HO, int WO, bool SCALE, int MODE>
__global__ __launch_bounds__(256) void dwconv(
    const unsigned short* __restrict__ in,
    const float* __restrict__ wt9,   // (9, NC) transposed
    const float* __restrict__ bias,  // (NC)
    unsigned short* __restrict__ outp)
{
    const int nc8 = NC/8;
    int idx = blockIdx.x*256 + threadIdx.x;
    if (idx >= NB*HO*WO*nc8) return;
    int c8 = idx % nc8; int rest = idx / nc8;
    int wo = rest % WO; rest /= WO;
    int ho = rest % HO; int b = rest / HO;
    int c0 = c8*8;
    f32x4 b0 = *(const f32x4*)&bias[c0];
    f32x4 b1 = *(const f32x4*)&bias[c0+4];
    float acc[8];
    #pragma unroll
    for (int j = 0; j < 4; ++j) { acc[j] = b0[j]; acc[j+4] = b1[j]; }
    #pragma unroll
    for (int kh = 0; kh < 3; ++kh) {
        int h = ho*S + kh - 1;
        if (h < 0 || h >= HH) continue;
        #pragma unroll
        for (int kw = 0; kw < 3; ++kw) {
            int ww = wo*S + kw - 1;
            if (ww < 0 || ww >= WW0) continue;
            int tap = kh*3 + kw;
            u16x8 xv = *(const u16x8*)&in[((size_t)b*(HH*WW0) + h*WW0 + ww)*NC + c0];
            f32x4 w0 = *(const f32x4*)&wt9[tap*NC + c0];
            f32x4 w1 = *(const f32x4*)&wt9[tap*NC + c0 + 4];
            #pragma unroll
            for (int j = 0; j < 4; ++j) {
                acc[j]   += bf2f(xv[j])   * w0[j];
                acc[j+4] += bf2f(xv[j+4]) * w1[j];
            }
        }
    }
    if (SCALE) {
        #pragma unroll
        for (int j = 0; j < 8; ++j) acc[j] *= QSCALE;
    }
    int tok = ho*WO + wo;
    int hh = c0 >> 6, d0 = c0 & 63;
    if (MODE == 0) {
        u16x8 ov;
        #pragma unroll
        for (int j = 0; j < 8; ++j) ov[j] = f2bf(acc[j]);
        *(u16x8*)&outp[((size_t)b*(HO*WO) + tok)*NC + c0] = ov;
    } else if (MODE == 1) {
        u16x8 ov;
        #pragma unroll
        for (int j = 0; j < 8; ++j) ov[j] = f2bf(acc[j]);
        *(u16x8*)&outp[((size_t)(b*NHEAD + hh)*(HO*WO) + tok)*HDIM + d0] = ov;
    } else {
        size_t base = ((size_t)(b*NHEAD + hh)*HDIM + d0)*(HO*WO) + tok;
        #pragma unroll
        for (int j = 0; j < 8; ++j)
            outp[base + (size_t)j*(HO*WO)] = f2bf(acc[j]);
    }
}

// ---------- attention ----------
// sign(s)*softmax(|s|), no max tracking, per-lane deferred denominator.
// LDS-staged K/V tiles (64 k), double-buffered, reg-staged with issue-early/write-late.
// XOR swizzle byte^=((row&7)<<4) on LDS (row%8==lq%8 -> per-lane constant): conflict-free.
__global__ __launch_bounds__(256) void attn_fwd(
    const unsigned short* __restrict__ Q,   // (NB, 3136, 384) bf16 pre-scaled by 0.125*log2e
    const unsigned short* __restrict__ Kpk, // (48, 784, 64) bf16 head-packed
    const unsigned short* __restrict__ Vt,  // (48, 64, 784) bf16 transposed
    unsigned short* __restrict__ ctx)       // (NB, 3136, 384) bf16
{
    __shared__ unsigned short lK[2][64*64];
    __shared__ unsigned short lV[2][64*64];
    const int bid = blockIdx.x;             // 1200 = 8 XCD * 6 bh * 25 qt
    const int xcd = bid & 7, slot = bid >> 3;
    const int bh = xcd*6 + slot/25;
    const int qt = slot % 25;
    const int b = bh / NHEAD, h = bh - b*NHEAD;
    const int t = threadIdx.x;
    const int w = t >> 6, l = t & 63;
    const int lq = l & 15, lg = l >> 4;
    const int wq0 = qt*128 + w*32;
    const int wq0c = (wq0 > NQTOK-32) ? (NQTOK-32) : wq0;   // clamp: all waves run barriers

    const unsigned short* Qb = Q + ((size_t)b*NQTOK + wq0c + lq)*NC + h*HDIM;
    s16x8 qA[2][2];
    qA[0][0] = *(const s16x8*)&Qb[lg*8];
    qA[0][1] = *(const s16x8*)&Qb[32 + lg*8];
    qA[1][0] = *(const s16x8*)&Qb[16*NC + lg*8];
    qA[1][1] = *(const s16x8*)&Qb[16*NC + 32 + lg*8];

    const char* Kg = (const char*)(Kpk + (size_t)bh*NKTOK*HDIM);
    const char* Vg = (const char*)(Vt + (size_t)bh*HDIM*NKTOK);
    char* lKb = (char*)lK;
    char* lVb = (char*)lV;

    // staging geometry: 512 x 16B chunks per 8KB tile; thread covers chunks t and t+256
    const int cr0 = t >> 3;           // rows 0..31
    const int cr1 = cr0 + 32;         // rows 32..63
    const int cc  = (t & 7) * 16;     // byte col in 128B row
    const int dst0 = cr0*128 + (cc ^ ((cr0 & 7) << 4));
    const int dst1 = cr1*128 + (cc ^ ((cr1 & 7) << 4));

    uint4 rk0, rk1, rv0, rv1;
    #define LOADT(kb) do { \
        rk0 = *(const uint4*)(Kg + (size_t)((kb) + cr0)*128 + cc); \
        rk1 = *(const uint4*)(Kg + (size_t)((kb) + cr1)*128 + cc); \
        rv0 = *(const uint4*)(Vg + (size_t)cr0*1568 + (kb)*2 + cc); \
        rv1 = *(const uint4*)(Vg + (size_t)cr1*1568 + (kb)*2 + cc); \
    } while(0)
    #define WRITET(buf) do { \
        *(uint4*)(lKb + (buf)*8192 + dst0) = rk0; \
        *(uint4*)(lKb + (buf)*8192 + dst1) = rk1; \
        *(uint4*)(lVb + (buf)*8192 + dst0) = rv0; \
        *(uint4*)(lVb + (buf)*8192 + dst1) = rv1; \
    } while(0)

    // per-lane swizzle constants for LDS reads (row%8 == lq%8 for 16-stride rows)
    const int swc = (lq & 7) << 4;
    const int ck0 = (lg*16) ^ swc;          // K frag half 0, byte col
    const int ck1 = (64 + lg*16) ^ swc;     // K frag half 1

    float ls[2] = {0.f, 0.f};
    f32x4 oacc[2][4] = {};

    LOADT(0);
    WRITET(0);
    __syncthreads();

    for (int kt = 0; kt < 12; ++kt) {
        const int cur = kt & 1;
        if (kt < 11) LOADT((kt+1)*64);
        // ---- compute tile kt from LDS[cur] ----
        const char* Kl = lKb + cur*8192;
        const char* Vl = lVb + cur*8192;
        f32x4 st[2][4] = {};
        __builtin_amdgcn_s_setprio(1);
        #pragma unroll
        for (int kfr = 0; kfr < 4; ++kfr) {
            int rb = (kfr*16 + lq)*128;
            s16x8 kf0 = *(const s16x8*)(Kl + rb + ck0);
            s16x8 kf1 = *(const s16x8*)(Kl + rb + ck1);
            st[0][kfr] = __builtin_amdgcn_mfma_f32_16x16x32_bf16(kf0, qA[0][0], st[0][kfr], 0,0,0);
            st[0][kfr] = __builtin_amdgcn_mfma_f32_16x16x32_bf16(kf1, qA[0][1], st[0][kfr], 0,0,0);
            st[1][kfr] = __builtin_amdgcn_mfma_f32_16x16x32_bf16(kf0, qA[1][0], st[1][kfr], 0,0,0);
            st[1][kfr] = __builtin_amdgcn_mfma_f32_16x16x32_bf16(kf1, qA[1][1], st[1][kfr], 0,0,0);
        }
        __builtin_amdgcn_s_setprio(0);
        s16x4 pbv[2][4];
        #pragma unroll
        for (int qf = 0; qf < 2; ++qf) {
            float rs = 0.f;
            #pragma unroll
            for (int kfr = 0; kfr < 4; ++kfr)
                #pragma unroll
                for (int r = 0; r < 4; ++r) {
                    float s = st[qf][kfr][r];
                    float e = exp2f(fabsf(s));
                    rs += e;
                    pbv[qf][kfr][r] = (short)f2bf(copysignf(e, s));
                }
            ls[qf] += rs;
        }
        __builtin_amdgcn_s_setprio(1);
        #pragma unroll
        for (int ks = 0; ks < 4; ++ks)
            #pragma unroll
            for (int f = 0; f < 4; ++f) {
                int va = (f*16 + lq)*128 + ((ks*32 + lg*8) ^ swc);
                s16x4 vvf = *(const s16x4*)(Vl + va);
                oacc[0][f] = __builtin_amdgcn_mfma_f32_16x16x16bf16_1k(vvf, pbv[0][ks], oacc[0][f], 0,0,0);
                oacc[1][f] = __builtin_amdgcn_mfma_f32_16x16x16bf16_1k(vvf, pbv[1][ks], oacc[1][f], 0,0,0);
            }
        __builtin_amdgcn_s_setprio(0);
        // ---- write next tile, one barrier per iter ----
        if (kt < 11) {
            WRITET(cur ^ 1);
            __syncthreads();
        }
    }
    // tail: k = 768..783 direct from global
    {
        const unsigned short* Kb2 = (const unsigned short*)Kg;
        const unsigned short* Vb2 = (const unsigned short*)Vg;
        const unsigned short* kr = &Kb2[(size_t)(768 + lq)*HDIM];
        s16x8 kf0 = *(const s16x8*)&kr[lg*8];
        s16x8 kf1 = *(const s16x8*)&kr[32 + lg*8];
        f32x4 st[2] = {};
        st[0] = __builtin_amdgcn_mfma_f32_16x16x32_bf16(kf0, qA[0][0], st[0], 0,0,0);
        st[0] = __builtin_amdgcn_mfma_f32_16x16x32_bf16(kf1, qA[0][1], st[0], 0,0,0);
        st[1] = __builtin_amdgcn_mfma_f32_16x16x32_bf16(kf0, qA[1][0], st[1], 0,0,0);
        st[1] = __builtin_amdgcn_mfma_f32_16x16x32_bf16(kf1, qA[1][1], st[1], 0,0,0);
        s16x4 vv[4];
        #pragma unroll
        for (int f = 0; f < 4; ++f)
            vv[f] = *(const s16x4*)&Vb2[(size_t)(f*16 + lq)*NKTOK + 768 + lg*4];
        s16x4 pbv[2];
        #pragma unroll
        for (int qf = 0; qf < 2; ++qf) {
            float rs = 0.f;
            #pragma unroll
            for (int r = 0; r < 4; ++r) {
                float s = st[qf][r];
                float e = exp2f(fabsf(s));
                rs += e;
                pbv[qf][r] = (short)f2bf(copysignf(e, s));
            }
            ls[qf] += rs;
        }
        #pragma unroll
        for (int f = 0; f < 4; ++f) {
            oacc[0][f] = __builtin_amdgcn_mfma_f32_16x16x16bf16_1k(vv[f], pbv[0], oacc[0][f], 0,0,0);
            oacc[1][f] = __builtin_amdgcn_mfma_f32_16x16x16bf16_1k(vv[f], pbv[1], oacc[1][f], 0,0,0);
        }
    }
    if (wq0 < NQTOK) {
        #pragma unroll
        for (int qf = 0; qf < 2; ++qf) {
            float lr2 = ls[qf];
            lr2 += __shfl_xor(lr2, 16);
            lr2 += __shfl_xor(lr2, 32);
            float inv = 1.f / lr2;
            unsigned short* cb = ctx + ((size_t)b*NQTOK + wq0 + qf*16 + lq)*NC + h*HDIM;
            #pragma unroll
            for (int f = 0; f < 4; ++f) {
                s16x4 o;
                #pragma unroll
                for (int r = 0; r < 4; ++r) o[r] = (short)f2bf(oacc[qf][f][r] * inv);
                *(s16x4*)&cb[f*16 + lg*4] = o;
            }
        }
    }
    #undef LOADT
    #undef WRITET
}

extern "C" void kernel_launch(void* const* d_in, const int* in_sizes, int n_in,
                              void* d_out, int out_size, void* d_ws, size_t ws_size,
                              hipStream_t stream)
{
    (void)in_sizes; (void)n_in; (void)out_size; (void)ws_size;
    const float* x      = (const float*)d_in[0];
    const float* q_w    = (const float*)d_in[3];
    const float* q_b    = (const float*)d_in[4];
    const float* k_w    = (const float*)d_in[5];
    const float* k_b    = (const float*)d_in[6];
    const float* v_w    = (const float*)d_in[7];
    const float* v_b    = (const float*)d_in[8];
    const float* q_dw_w = (const float*)d_in[9];
    const float* q_dw_b = (const float*)d_in[10];
    const float* k_dw_w = (const float*)d_in[11];
    const float* k_dw_b = (const float*)d_in[12];
    const float* v_dw_w = (const float*)d_in[13];
    const float* v_dw_b = (const float*)d_in[14];
    const float* proj_w = (const float*)d_in[15];
    const float* proj_b = (const float*)d_in[16];
    float* outf = (float*)d_out;
    unsigned short* ws  = (unsigned short*)d_ws;

    const size_t nQ  = (size_t)NB*NQTOK*NC;   // 9,633,792 elems
    const size_t nKc = (size_t)NB*NKTOK*NC;   // 2,408,448 elems
    unsigned short* preQ = ws;                // bf16 pre-conv Q
    unsigned short* preK = ws + nQ;           // bf16 pre-conv K; later ctx
    unsigned short* Kpk  = ws + 2*nQ;         // bf16 post-conv K, head-packed (bh,k,64)
    unsigned short* Vt   = Kpk + nKc;         // bf16 post-conv V, transposed (bh,d,k)
    unsigned short* wbf  = Vt + nKc;          // bf16 [4][384*384] dense weights
    float* wtab = (float*)(wbf + (size_t)4*NC*NC);   // [3][9][384] dw weights transposed
    float* ball = wtab + 3*9*NC;              // [4][384] biases
    unsigned short* preV = (unsigned short*)d_out;          // d_out lower half
    unsigned short* Qc   = (unsigned short*)d_out;          // after preV consumed
    unsigned short* xbf  = ((unsigned short*)d_out) + nQ;   // d_out upper half: bf16 x
    unsigned short* ctx  = preK;              // reuse preK after k-conv

    // 0. prep: dtype conversions + weight transposes
    cvt_bf16<<<dim3(4704), dim3(256), 0, stream>>>(x, xbf, (int)(nQ/8));
    cvt_w4  <<<dim3(288),  dim3(256), 0, stream>>>(q_w, k_w, v_w, proj_w, wbf);
    cvt_bias<<<dim3(6),    dim3(256), 0, stream>>>(q_b, k_b, v_b, proj_b, ball);
    prep_w  <<<dim3(41),   dim3(256), 0, stream>>>(q_dw_w, k_dw_w, v_dw_w, wtab);
    // 1. QKV projections (bf16 x bf16): Q->preQ, K->preK, V->preV(d_out)
    gemm_bt_bf<false><<<dim3(196*9), dim3(256), 0, stream>>>(
        xbf, wbf, ball, preQ, preK, preV, nullptr, 9);
    // 2. depthwise convs; K head-packed, V transposed, Q scaled by 0.125*log2e
    dwconv<2,28,28,false,1><<<dim3(1176), dim3(256), 0, stream>>>(preK, wtab + 1*9*NC, k_dw_b, Kpk);
    dwconv<2,28,28,false,2><<<dim3(1176), dim3(256), 0, stream>>>(preV, wtab + 2*9*NC, v_dw_b, Vt);
    dwconv<1,56,56,true ,0><<<dim3(4704), dim3(256), 0, stream>>>(preQ, wtab + 0*9*NC, q_dw_b, Qc);
    // 3. attention
    attn_fwd<<<dim3(1200), dim3(256), 0, stream>>>(Qc, Kpk, Vt, ctx);
    // 4. output projection -> f32 d_out
    gemm_bt_bf<true><<<dim3(196*3), dim3(256), 0, stream>>>(
        ctx, wbf + (size_t)3*NC*NC, ball + 3*NC, nullptr, nullptr, nullptr, outf, 3);
}